// Round 1
// baseline (2480.179 us; speedup 1.0000x reference)
//
#include <hip/hip_runtime.h>
#include <hip/hip_bf16.h>
#include <math.h>

// Problem constants
#define BB 4
#define NN 2048
#define CC 256
#define HH 8
#define DH 32
#define LL 2
#define SS 16          // number of selected points (B x 16 channels argmax)
#define KK 33          // 1 + NSAMPLE
#define NSAMPLE 32
#define EPSV 1e-5f

// ---------------------------------------------------------------------------
// Transpose per batch: in (R x Ccols) -> out (Ccols x R)
// grid (Ccols/32, R/32, B), block (32, 8)
__global__ __launch_bounds__(256) void transpose_k(const float* __restrict__ in,
                                                   float* __restrict__ out,
                                                   int R, int Ccols) {
    __shared__ float t[32][33];
    int n0 = blockIdx.x * 32, c0 = blockIdx.y * 32, b = blockIdx.z;
    const float* ip = in + (size_t)b * R * Ccols;
    float* op = out + (size_t)b * R * Ccols;
    int tx = threadIdx.x, ty = threadIdx.y;
#pragma unroll
    for (int i = 0; i < 4; ++i)
        t[ty + i * 8][tx] = ip[(size_t)(c0 + ty + i * 8) * Ccols + n0 + tx];
    __syncthreads();
#pragma unroll
    for (int i = 0; i < 4; ++i)
        op[(size_t)(n0 + ty + i * 8) * R + c0 + tx] = t[tx][ty + i * 8];
}

// ---------------------------------------------------------------------------
// Generic fp32 GEMM: C[m,n] = sum_k A[m,k] * (TRANSB ? B[n,k] : B[k,n]) (+bias[n])
// 64x64 tile, 256 threads, each 4x4. Bounds-checked.
template <bool TRANSB, bool BIAS>
__global__ __launch_bounds__(256) void gemm_k(const float* __restrict__ A,
                                              const float* __restrict__ Bm,
                                              const float* __restrict__ bias,
                                              float* __restrict__ Cm,
                                              int M, int Nc, int K) {
    __shared__ float As[16][68];  // As[k][m]
    __shared__ float Bs[16][68];  // Bs[k][n]
    int t = threadIdx.x;
    int tx = t & 15, ty = t >> 4;
    int row0 = blockIdx.y * 64, col0 = blockIdx.x * 64;
    float acc[4][4] = {};
    for (int k0 = 0; k0 < K; k0 += 16) {
#pragma unroll
        for (int p = 0; p < 4; ++p) {
            int i = t + 256 * p;
            int m = i >> 4, k = i & 15;
            int gm = row0 + m, gk = k0 + k;
            As[k][m] = (gm < M && gk < K) ? A[(size_t)gm * K + gk] : 0.f;
        }
#pragma unroll
        for (int p = 0; p < 4; ++p) {
            int i = t + 256 * p;
            if (TRANSB) {
                int k = i & 15, n = i >> 4;
                int gn = col0 + n, gk = k0 + k;
                Bs[k][n] = (gn < Nc && gk < K) ? Bm[(size_t)gn * K + gk] : 0.f;
            } else {
                int n = i & 63, k = i >> 6;
                int gn = col0 + n, gk = k0 + k;
                Bs[k][n] = (gn < Nc && gk < K) ? Bm[(size_t)gk * Nc + gn] : 0.f;
            }
        }
        __syncthreads();
#pragma unroll
        for (int kk = 0; kk < 16; ++kk) {
            float4 a4 = *(const float4*)&As[kk][ty * 4];
            float4 b4 = *(const float4*)&Bs[kk][tx * 4];
            float av[4] = {a4.x, a4.y, a4.z, a4.w};
            float bv[4] = {b4.x, b4.y, b4.z, b4.w};
#pragma unroll
            for (int i = 0; i < 4; ++i)
#pragma unroll
                for (int j = 0; j < 4; ++j) acc[i][j] = fmaf(av[i], bv[j], acc[i][j]);
        }
        __syncthreads();
    }
#pragma unroll
    for (int i = 0; i < 4; ++i) {
        int r = row0 + ty * 4 + i;
        if (r >= M) continue;
#pragma unroll
        for (int j = 0; j < 4; ++j) {
            int c = col0 + tx * 4 + j;
            if (c >= Nc) continue;
            float v = acc[i][j];
            if (BIAS) v += bias[c];
            Cm[(size_t)r * Nc + c] = v;
        }
    }
}

// ---------------------------------------------------------------------------
// Flash-style fp32 attention. One thread per query row. grid (N/256, B*H), block 256.
#define AKT 32
__global__ __launch_bounds__(256) void attn_k(const float* __restrict__ Q,
                                              const float* __restrict__ Kg,
                                              const float* __restrict__ Vg,
                                              float* __restrict__ O) {
    __shared__ float Ks[AKT][32];
    __shared__ float Vs[AKT][32];
    int t = threadIdx.x;
    int bh = blockIdx.y;
    int b = bh >> 3, h = bh & 7;
    int n = blockIdx.x * 256 + t;
    const float scale = 0.17677669529663687f;  // 1/sqrt(32)
    const float* qp = Q + ((size_t)(b * NN + n)) * CC + h * DH;
    float4 q[8];
#pragma unroll
    for (int i = 0; i < 8; ++i) {
        q[i] = *(const float4*)(qp + i * 4);
        q[i].x *= scale; q[i].y *= scale; q[i].z *= scale; q[i].w *= scale;
    }
    float4 o[8];
#pragma unroll
    for (int i = 0; i < 8; ++i) { o[i].x = 0.f; o[i].y = 0.f; o[i].z = 0.f; o[i].w = 0.f; }
    float mrun = -1e30f, l = 0.f;

    int j = t >> 3, d4 = t & 7;
    for (int m0 = 0; m0 < NN; m0 += AKT) {
        size_t gidx = ((size_t)(b * NN + m0 + j)) * CC + h * DH + d4 * 4;
        float4 kv = *(const float4*)(Kg + gidx);
        float4 vv = *(const float4*)(Vg + gidx);
        __syncthreads();  // previous tile fully consumed
        *(float4*)&Ks[j][d4 * 4] = kv;
        *(float4*)&Vs[j][d4 * 4] = vv;
        __syncthreads();

        float sarr[AKT];
#pragma unroll
        for (int jj = 0; jj < AKT; ++jj) {
            const float4* kr = (const float4*)Ks[jj];
            float s0 = 0.f, s1 = 0.f, s2 = 0.f, s3 = 0.f;
#pragma unroll
            for (int i = 0; i < 8; ++i) {
                float4 k4 = kr[i];
                s0 = fmaf(q[i].x, k4.x, s0);
                s1 = fmaf(q[i].y, k4.y, s1);
                s2 = fmaf(q[i].z, k4.z, s2);
                s3 = fmaf(q[i].w, k4.w, s3);
            }
            sarr[jj] = (s0 + s1) + (s2 + s3);
        }
        float tm = sarr[0];
#pragma unroll
        for (int jj = 1; jj < AKT; ++jj) tm = fmaxf(tm, sarr[jj]);
        float nm = fmaxf(mrun, tm);
        float corr = __expf(mrun - nm);
        l *= corr;
#pragma unroll
        for (int i = 0; i < 8; ++i) {
            o[i].x *= corr; o[i].y *= corr; o[i].z *= corr; o[i].w *= corr;
        }
#pragma unroll
        for (int jj = 0; jj < AKT; ++jj) {
            float p = __expf(sarr[jj] - nm);
            l += p;
            const float4* vr = (const float4*)Vs[jj];
#pragma unroll
            for (int i = 0; i < 8; ++i) {
                float4 v4 = vr[i];
                o[i].x = fmaf(p, v4.x, o[i].x);
                o[i].y = fmaf(p, v4.y, o[i].y);
                o[i].z = fmaf(p, v4.z, o[i].z);
                o[i].w = fmaf(p, v4.w, o[i].w);
            }
        }
        mrun = nm;
    }
    float inv = 1.f / l;
    float* op = O + ((size_t)(b * NN + n)) * CC + h * DH;
#pragma unroll
    for (int i = 0; i < 8; ++i) {
        float4 r;
        r.x = o[i].x * inv; r.y = o[i].y * inv; r.z = o[i].z * inv; r.w = o[i].w * inv;
        *(float4*)(op + i * 4) = r;
    }
}

// ---------------------------------------------------------------------------
// X = LayerNorm(X + P) per row of 256. One wave per row, 4 rows per block.
__global__ __launch_bounds__(256) void add_ln_k(float* __restrict__ X,
                                                const float* __restrict__ P,
                                                const float* __restrict__ g,
                                                const float* __restrict__ bta) {
    int wave = threadIdx.x >> 6, lane = threadIdx.x & 63;
    size_t row = (size_t)blockIdx.x * 4 + wave;
    float4 x = *(float4*)(X + row * CC + lane * 4);
    float4 p = *(const float4*)(P + row * CC + lane * 4);
    x.x += p.x; x.y += p.y; x.z += p.z; x.w += p.w;
    float sum = x.x + x.y + x.z + x.w;
    float ss = x.x * x.x + x.y * x.y + x.z * x.z + x.w * x.w;
#pragma unroll
    for (int off = 32; off; off >>= 1) {
        sum += __shfl_down(sum, off);
        ss += __shfl_down(ss, off);
    }
    sum = __shfl(sum, 0);
    ss = __shfl(ss, 0);
    float mean = sum * (1.f / 256.f);
    float var = ss * (1.f / 256.f) - mean * mean;
    float w = rsqrtf(var + EPSV);
    float4 gg = *(const float4*)(g + lane * 4);
    float4 bb = *(const float4*)(bta + lane * 4);
    x.x = (x.x - mean) * w * gg.x + bb.x;
    x.y = (x.y - mean) * w * gg.y + bb.y;
    x.z = (x.z - mean) * w * gg.z + bb.z;
    x.w = (x.w - mean) * w * gg.w + bb.w;
    *(float4*)(X + row * CC + lane * 4) = x;
}

// ---------------------------------------------------------------------------
// Per-channel (column) stats over M rows: stats[c]=mean, stats[Cc+c]=biased var.
__global__ __launch_bounds__(256) void bn_stats_k(const float* __restrict__ Hm,
                                                  float* __restrict__ stats,
                                                  int M, int Cc) {
    int c = blockIdx.x;
    int t = threadIdx.x;
    float s = 0.f, ss = 0.f;
    for (int r = t; r < M; r += 256) {
        float v = Hm[(size_t)r * Cc + c];
        s += v;
        ss += v * v;
    }
    __shared__ float sh0[256], sh1[256];
    sh0[t] = s; sh1[t] = ss;
    __syncthreads();
    for (int st = 128; st; st >>= 1) {
        if (t < st) { sh0[t] += sh0[t + st]; sh1[t] += sh1[t + st]; }
        __syncthreads();
    }
    if (t == 0) {
        float mean = sh0[0] / (float)M;
        stats[c] = mean;
        stats[Cc + c] = sh1[0] / (float)M - mean * mean;
    }
}

// Apply BN + (leaky)ReLU elementwise. alpha=0 -> relu, 0.2 -> leaky relu.
template <bool BIAS>
__global__ __launch_bounds__(256) void bn_apply_k(const float* __restrict__ in,
                                                  float* __restrict__ out,
                                                  const float* __restrict__ stats,
                                                  const float* __restrict__ gam,
                                                  const float* __restrict__ bet,
                                                  int total, int Cc, float alpha) {
    int i = blockIdx.x * 256 + threadIdx.x;
    if (i >= total) return;
    int c = i % Cc;
    float mean = stats[c], var = stats[Cc + c];
    float v = (in[i] - mean) * rsqrtf(var + EPSV) * gam[c] + bet[c];
    out[i] = v > 0.f ? v : alpha * v;
}

// ---------------------------------------------------------------------------
// Argmax over n for each (b, c in 0..15); also gather the selected point coords.
__global__ __launch_bounds__(64) void argmax_k(const float* __restrict__ H3,
                                               int* __restrict__ idxo,
                                               float* __restrict__ qpts,
                                               const float* __restrict__ pts) {
    int bc = blockIdx.x;
    int b = bc >> 4;
    int lane = threadIdx.x;
    float best = -1e30f;
    int bn = 0;
    for (int n = lane; n < NN; n += 64) {
        float v = H3[((size_t)(b * NN + n)) * 16 + (bc & 15)];
        if (v > best) { best = v; bn = n; }
    }
#pragma unroll
    for (int off = 32; off; off >>= 1) {
        float ov = __shfl_xor(best, off);
        int on = __shfl_xor(bn, off);
        if (ov > best || (ov == best && on < bn)) { best = ov; bn = on; }
    }
    if (lane == 0) idxo[bc] = bn;
    if (lane < 3) qpts[bc * 3 + lane] = pts[(size_t)b * 3 * NN + lane * NN + bn];
}

// ---------------------------------------------------------------------------
// Ball query: first NSAMPLE in-order indices with sqd <= R^2, padded with first.
// One wave per (b,s). Uses the reference's |q|^2+|p|^2-2qp formula structure.
__global__ __launch_bounds__(64) void ball_k(const float* __restrict__ pts,
                                             const float* __restrict__ qpts,
                                             int* __restrict__ gi) {
    int bs = blockIdx.x;
    int b = bs >> 4;
    int lane = threadIdx.x;
    float qx = qpts[bs * 3], qy = qpts[bs * 3 + 1], qz = qpts[bs * 3 + 2];
    float qq = (qx * qx + qy * qy) + qz * qz;
    const float* px = pts + (size_t)b * 3 * NN;
    const float R2 = 0.09f;
    int cnt = 0;
    for (int base = 0; base < NN && cnt < NSAMPLE; base += 64) {
        int n = base + lane;
        float x = px[n], y = px[NN + n], z = px[2 * NN + n];
        float pp = (x * x + y * y) + z * z;
        float dot = (qx * x + qy * y) + qz * z;
        float sqd = (qq + pp) - 2.f * dot;
        bool ok = !(sqd > R2);
        unsigned long long mk = __ballot(ok);
        int pos = cnt + (int)__popcll(mk & ((1ull << lane) - 1ull));
        if (ok && pos < NSAMPLE) gi[bs * NSAMPLE + pos] = n;
        cnt += (int)__popcll(mk);
    }
    __syncthreads();
    int g0 = gi[bs * NSAMPLE];  // cnt >= 1 always (query point itself)
    if (lane >= cnt && lane < NSAMPLE) gi[bs * NSAMPLE + lane] = g0;
}

// ---------------------------------------------------------------------------
// Build grouped coordinates G0: rows (b,s,k) x 3 cols.
__global__ __launch_bounds__(256) void gather_k(const float* __restrict__ pts,
                                                const float* __restrict__ qpts,
                                                const int* __restrict__ gi,
                                                float* __restrict__ G0) {
    int e = blockIdx.x * 256 + threadIdx.x;
    if (e >= BB * SS * KK * 3) return;
    int r = e / 3, d = e % 3;
    int k = r % KK;
    int bs = r / KK;
    int b = bs >> 4;
    float v;
    if (k == 0)
        v = qpts[bs * 3 + d];
    else
        v = pts[(size_t)b * 3 * NN + d * NN + gi[bs * NSAMPLE + k - 1]];
    G0[e] = v;
}

// ---------------------------------------------------------------------------
// Max over k: out[(b*512+o)*16 + s] = max_k G3[((b*16+s)*33+k)*512 + o]
__global__ __launch_bounds__(256) void maxpool_k(const float* __restrict__ G3,
                                                 float* __restrict__ out) {
    int i = blockIdx.x * 256 + threadIdx.x;
    if (i >= BB * 512 * SS) return;
    int o = i & 511;
    int s = (i >> 9) & 15;
    int b = i >> 13;
    const float* p = G3 + ((size_t)(b * SS + s) * KK) * 512 + o;
    float mx = p[0];
#pragma unroll
    for (int k = 1; k < KK; ++k) mx = fmaxf(mx, p[(size_t)k * 512]);
    out[((size_t)(b * 512 + o)) * SS + s] = mx;
}

// ---------------------------------------------------------------------------
extern "C" void kernel_launch(void* const* d_in, const int* in_sizes, int n_in,
                              void* d_out, int out_size, void* d_ws, size_t ws_size,
                              hipStream_t stream) {
    const float* hoch = (const float*)d_in[0];
    const float* pts = (const float*)d_in[1];
    const float* Wq = (const float*)d_in[2];
    const float* Wk = (const float*)d_in[3];
    const float* Wv = (const float*)d_in[4];
    const float* Wo = (const float*)d_in[5];
    const float* ln_g = (const float*)d_in[6];
    const float* ln_b = (const float*)d_in[7];
    const float* fg_w1 = (const float*)d_in[8];
    const float* fg_b1 = (const float*)d_in[9];
    const float* fg_w2 = (const float*)d_in[10];
    const float* fg_b2 = (const float*)d_in[11];
    const float* fg_w3 = (const float*)d_in[12];
    const float* fg_b3 = (const float*)d_in[13];
    const float* fg_g1 = (const float*)d_in[14];
    const float* fg_be1 = (const float*)d_in[15];
    const float* fg_g2 = (const float*)d_in[16];
    const float* fg_be2 = (const float*)d_in[17];
    const float* fg_g3 = (const float*)d_in[18];
    const float* fg_be3 = (const float*)d_in[19];
    const float* cw1 = (const float*)d_in[20];
    const float* cw2 = (const float*)d_in[21];
    const float* cw3 = (const float*)d_in[22];
    const float* cg1 = (const float*)d_in[23];
    const float* cb1 = (const float*)d_in[24];
    const float* cg2 = (const float*)d_in[25];
    const float* cb2 = (const float*)d_in[26];
    const float* cg3 = (const float*)d_in[27];
    const float* cb3 = (const float*)d_in[28];
    float* out = (float*)d_out;

    float* ws = (float*)d_ws;
    const size_t MSZ = (size_t)BB * NN * CC;  // 2,097,152 floats
    float* X = ws;
    float* bA = ws + MSZ;
    float* bB = ws + 2 * MSZ;
    float* bC = ws + 3 * MSZ;
    float* bD = ws + 4 * MSZ;
    float* sm = ws + 5 * MSZ;
    float* stats = sm;              // 1024 floats
    float* qpts = sm + 1024;        // 192
    int* idx = (int*)(sm + 1536);   // 64 ints
    int* gi = (int*)(sm + 1664);    // 2048 ints
    float* G0 = sm + 4096;          // 6336

    // x = hoch.transpose(0,2,1): (B,C,N) -> (B,N,C)
    transpose_k<<<dim3(NN / 32, CC / 32, BB), dim3(32, 8), 0, stream>>>(hoch, X, CC, NN);

    const int Mrows = BB * NN;  // 8192
    dim3 gProj(CC / 64, Mrows / 64);  // (4,128)
    for (int l = 0; l < LL; ++l) {
        const float* wq = Wq + (size_t)l * CC * CC;
        const float* wk = Wk + (size_t)l * CC * CC;
        const float* wv = Wv + (size_t)l * CC * CC;
        const float* wo = Wo + (size_t)l * CC * CC;
        gemm_k<false, false><<<gProj, 256, 0, stream>>>(X, wq, nullptr, bA, Mrows, CC, CC);
        gemm_k<false, false><<<gProj, 256, 0, stream>>>(X, wk, nullptr, bB, Mrows, CC, CC);
        gemm_k<false, false><<<gProj, 256, 0, stream>>>(X, wv, nullptr, bC, Mrows, CC, CC);
        attn_k<<<dim3(NN / 256, BB * HH), 256, 0, stream>>>(bA, bB, bC, bD);
        gemm_k<false, false><<<gProj, 256, 0, stream>>>(bD, wo, nullptr, bA, Mrows, CC, CC);
        add_ln_k<<<Mrows / 4, 256, 0, stream>>>(X, bA, ln_g + l * CC, ln_b + l * CC);
    }

    // fg head: 256 -> 64 -> 32 -> 16, BN+ReLU each
    gemm_k<true, true><<<dim3(1, Mrows / 64), 256, 0, stream>>>(X, fg_w1, fg_b1, bA, Mrows, 64, 256);
    bn_stats_k<<<64, 256, 0, stream>>>(bA, stats, Mrows, 64);
    bn_apply_k<true><<<(Mrows * 64 + 255) / 256, 256, 0, stream>>>(bA, bA, stats, fg_g1, fg_be1, Mrows * 64, 64, 0.f);
    gemm_k<true, true><<<dim3(1, Mrows / 64), 256, 0, stream>>>(bA, fg_w2, fg_b2, bB, Mrows, 32, 64);
    bn_stats_k<<<32, 256, 0, stream>>>(bB, stats, Mrows, 32);
    bn_apply_k<true><<<(Mrows * 32 + 255) / 256, 256, 0, stream>>>(bB, bB, stats, fg_g2, fg_be2, Mrows * 32, 32, 0.f);
    gemm_k<true, true><<<dim3(1, Mrows / 64), 256, 0, stream>>>(bB, fg_w3, fg_b3, bC, Mrows, 16, 32);
    bn_stats_k<<<16, 256, 0, stream>>>(bC, stats, Mrows, 16);
    bn_apply_k<true><<<(Mrows * 16 + 255) / 256, 256, 0, stream>>>(bC, bC, stats, fg_g3, fg_be3, Mrows * 16, 16, 0.f);

    // point selection + ball query + grouping
    argmax_k<<<BB * SS, 64, 0, stream>>>(bC, idx, qpts, pts);
    ball_k<<<BB * SS, 64, 0, stream>>>(pts, qpts, gi);
    gather_k<<<(BB * SS * KK * 3 + 255) / 256, 256, 0, stream>>>(pts, qpts, gi, G0);

    // conv stack on grouped points: 3 -> 64 -> 256 -> 512, BN+LeakyReLU(0.2)
    const int Mg = BB * SS * KK;  // 2112
    gemm_k<true, false><<<dim3(1, Mg / 64), 256, 0, stream>>>(G0, cw1, nullptr, bA, Mg, 64, 3);
    bn_stats_k<<<64, 256, 0, stream>>>(bA, stats, Mg, 64);
    bn_apply_k<false><<<(Mg * 64 + 255) / 256, 256, 0, stream>>>(bA, bA, stats, cg1, cb1, Mg * 64, 64, 0.2f);
    gemm_k<true, false><<<dim3(4, Mg / 64), 256, 0, stream>>>(bA, cw2, nullptr, bB, Mg, 256, 64);
    bn_stats_k<<<256, 256, 0, stream>>>(bB, stats, Mg, 256);
    bn_apply_k<false><<<(Mg * 256 + 255) / 256, 256, 0, stream>>>(bB, bB, stats, cg2, cb2, Mg * 256, 256, 0.2f);
    gemm_k<true, false><<<dim3(8, Mg / 64), 256, 0, stream>>>(bB, cw3, nullptr, bC, Mg, 512, 256);
    bn_stats_k<<<512, 256, 0, stream>>>(bC, stats, Mg, 512);
    bn_apply_k<false><<<(Mg * 512 + 255) / 256, 256, 0, stream>>>(bC, bC, stats, cg3, cb3, Mg * 512, 512, 0.2f);

    // final max over k
    maxpool_k<<<(BB * 512 * SS + 255) / 256, 256, 0, stream>>>(bC, out);

    (void)in_sizes; (void)n_in; (void)out_size; (void)ws_size; (void)idx;
}

// Round 2
// 883.237 us; speedup vs baseline: 2.8081x; 2.8081x over previous
//
#include <hip/hip_runtime.h>
#include <hip/hip_bf16.h>
#include <math.h>

// Problem constants
#define BB 4
#define NN 2048
#define CC 256
#define HH 8
#define DH 32
#define LL 2
#define SS 16          // number of selected points (B x 16 channels argmax)
#define KK 33          // 1 + NSAMPLE
#define NSAMPLE 32
#define EPSV 1e-5f

typedef _Float16 f16x8 __attribute__((ext_vector_type(8)));
typedef _Float16 f16x4 __attribute__((ext_vector_type(4)));
typedef float f32x4 __attribute__((ext_vector_type(4)));

// ---------------------------------------------------------------------------
// Transpose per batch: in (R x Ccols) -> out (Ccols x R)
__global__ __launch_bounds__(256) void transpose_k(const float* __restrict__ in,
                                                   float* __restrict__ out,
                                                   int R, int Ccols) {
    __shared__ float t[32][33];
    int n0 = blockIdx.x * 32, c0 = blockIdx.y * 32, b = blockIdx.z;
    const float* ip = in + (size_t)b * R * Ccols;
    float* op = out + (size_t)b * R * Ccols;
    int tx = threadIdx.x, ty = threadIdx.y;
#pragma unroll
    for (int i = 0; i < 4; ++i)
        t[ty + i * 8][tx] = ip[(size_t)(c0 + ty + i * 8) * Ccols + n0 + tx];
    __syncthreads();
#pragma unroll
    for (int i = 0; i < 4; ++i)
        op[(size_t)(n0 + ty + i * 8) * R + c0 + tx] = t[tx][ty + i * 8];
}

// ---------------------------------------------------------------------------
// Generic fp32 GEMM (unchanged from round 1)
template <bool TRANSB, bool BIAS>
__global__ __launch_bounds__(256) void gemm_k(const float* __restrict__ A,
                                              const float* __restrict__ Bm,
                                              const float* __restrict__ bias,
                                              float* __restrict__ Cm,
                                              int M, int Nc, int K) {
    __shared__ float As[16][68];
    __shared__ float Bs[16][68];
    int t = threadIdx.x;
    int tx = t & 15, ty = t >> 4;
    int row0 = blockIdx.y * 64, col0 = blockIdx.x * 64;
    float acc[4][4] = {};
    for (int k0 = 0; k0 < K; k0 += 16) {
#pragma unroll
        for (int p = 0; p < 4; ++p) {
            int i = t + 256 * p;
            int m = i >> 4, k = i & 15;
            int gm = row0 + m, gk = k0 + k;
            As[k][m] = (gm < M && gk < K) ? A[(size_t)gm * K + gk] : 0.f;
        }
#pragma unroll
        for (int p = 0; p < 4; ++p) {
            int i = t + 256 * p;
            if (TRANSB) {
                int k = i & 15, n = i >> 4;
                int gn = col0 + n, gk = k0 + k;
                Bs[k][n] = (gn < Nc && gk < K) ? Bm[(size_t)gn * K + gk] : 0.f;
            } else {
                int n = i & 63, k = i >> 6;
                int gn = col0 + n, gk = k0 + k;
                Bs[k][n] = (gn < Nc && gk < K) ? Bm[(size_t)gk * Nc + gn] : 0.f;
            }
        }
        __syncthreads();
#pragma unroll
        for (int kk = 0; kk < 16; ++kk) {
            float4 a4 = *(const float4*)&As[kk][ty * 4];
            float4 b4 = *(const float4*)&Bs[kk][tx * 4];
            float av[4] = {a4.x, a4.y, a4.z, a4.w};
            float bv[4] = {b4.x, b4.y, b4.z, b4.w};
#pragma unroll
            for (int i = 0; i < 4; ++i)
#pragma unroll
                for (int j = 0; j < 4; ++j) acc[i][j] = fmaf(av[i], bv[j], acc[i][j]);
        }
        __syncthreads();
    }
#pragma unroll
    for (int i = 0; i < 4; ++i) {
        int r = row0 + ty * 4 + i;
        if (r >= M) continue;
#pragma unroll
        for (int j = 0; j < 4; ++j) {
            int c = col0 + tx * 4 + j;
            if (c >= Nc) continue;
            float v = acc[i][j];
            if (BIAS) v += bias[c];
            Cm[(size_t)r * Nc + c] = v;
        }
    }
}

// ---------------------------------------------------------------------------
// Split-fp16 MFMA flash attention.
// Each block: 256 threads = 4 waves, one (b,h), 64 queries (16 per wave).
// Loops over 64 K-tiles of 32 keys. S computed transposed (K·Q^T) so
// softmax is in-lane + 2 shfl; P transposed via per-wave LDS round-trip;
// O accumulated as O^T = V^T·P^T (two 16-d halves).
// Split precision: x = hi + lo (fp16); products hi·hi + hi·lo + lo·hi.
#define PROW 40
__global__ __launch_bounds__(256) void attn_mfma(const float* __restrict__ Q,
                                                 const float* __restrict__ Kg,
                                                 const float* __restrict__ Vg,
                                                 float* __restrict__ O) {
    __shared__ _Float16 sKhi[32 * PROW];
    __shared__ _Float16 sKlo[32 * PROW];
    __shared__ _Float16 sVhi[32 * PROW];   // transposed: [d][key]
    __shared__ _Float16 sVlo[32 * PROW];
    __shared__ _Float16 sPhi[4][16 * PROW];
    __shared__ _Float16 sPlo[4][16 * PROW];

    int t = threadIdx.x;
    int w = t >> 6;
    int lane = t & 63;
    int col = lane & 15;
    int quad = lane >> 4;
    int bh = blockIdx.y;
    int b = bh >> 3, h = bh & 7;
    int q0 = blockIdx.x * 64 + w * 16;

    const float scale = 0.17677669529663687f;  // 1/sqrt(32)

    // Load Q fragment (B-operand layout: [q=col][d=quad*8+j]), scale, split.
    const float* qp = Q + ((size_t)(b * NN + q0 + col)) * CC + h * DH + quad * 8;
    f16x8 qhi, qlo;
    {
        float4 qa = *(const float4*)qp;
        float4 qb = *(const float4*)(qp + 4);
        float qv[8] = {qa.x, qa.y, qa.z, qa.w, qb.x, qb.y, qb.z, qb.w};
#pragma unroll
        for (int j = 0; j < 8; ++j) {
            float v = qv[j] * scale;
            _Float16 hi = (_Float16)v;
            qhi[j] = hi;
            qlo[j] = (_Float16)(v - (float)hi);
        }
    }

    f32x4 o0 = {0.f, 0.f, 0.f, 0.f}, o1 = {0.f, 0.f, 0.f, 0.f};
    float mrun = -1e30f, lsum = 0.f;

    // staging indices
    int skey = t >> 3, sd = (t & 7) * 4;
    const float* Kbase = Kg + ((size_t)(b * NN)) * CC + h * DH;
    const float* Vbase = Vg + ((size_t)(b * NN)) * CC + h * DH;

    for (int k0 = 0; k0 < NN; k0 += 32) {
        float4 kf = *(const float4*)(Kbase + (size_t)(k0 + skey) * CC + sd);
        float4 vf = *(const float4*)(Vbase + (size_t)(k0 + skey) * CC + sd);
        __syncthreads();  // previous tile fully consumed
        {
            float kv[4] = {kf.x, kf.y, kf.z, kf.w};
            f16x4 khv, klv;
#pragma unroll
            for (int j = 0; j < 4; ++j) {
                _Float16 hi = (_Float16)kv[j];
                khv[j] = hi;
                klv[j] = (_Float16)(kv[j] - (float)hi);
            }
            *(f16x4*)&sKhi[skey * PROW + sd] = khv;
            *(f16x4*)&sKlo[skey * PROW + sd] = klv;
            float vv[4] = {vf.x, vf.y, vf.z, vf.w};
#pragma unroll
            for (int j = 0; j < 4; ++j) {
                _Float16 hi = (_Float16)vv[j];
                sVhi[(sd + j) * PROW + skey] = hi;
                sVlo[(sd + j) * PROW + skey] = (_Float16)(vv[j] - (float)hi);
            }
        }
        __syncthreads();

        // QK^T (transposed): S^T tiles for key subtiles 0,1
        f16x8 kh0 = *(const f16x8*)&sKhi[col * PROW + quad * 8];
        f16x8 kl0 = *(const f16x8*)&sKlo[col * PROW + quad * 8];
        f16x8 kh1 = *(const f16x8*)&sKhi[(16 + col) * PROW + quad * 8];
        f16x8 kl1 = *(const f16x8*)&sKlo[(16 + col) * PROW + quad * 8];
        f32x4 s0 = {0.f, 0.f, 0.f, 0.f}, s1 = {0.f, 0.f, 0.f, 0.f};
        s0 = __builtin_amdgcn_mfma_f32_16x16x32_f16(kh0, qhi, s0, 0, 0, 0);
        s0 = __builtin_amdgcn_mfma_f32_16x16x32_f16(kh0, qlo, s0, 0, 0, 0);
        s0 = __builtin_amdgcn_mfma_f32_16x16x32_f16(kl0, qhi, s0, 0, 0, 0);
        s1 = __builtin_amdgcn_mfma_f32_16x16x32_f16(kh1, qhi, s1, 0, 0, 0);
        s1 = __builtin_amdgcn_mfma_f32_16x16x32_f16(kh1, qlo, s1, 0, 0, 0);
        s1 = __builtin_amdgcn_mfma_f32_16x16x32_f16(kl1, qhi, s1, 0, 0, 0);

        // online softmax (per query col; entries spread over quads via shfl)
        float sv[8] = {s0.x, s0.y, s0.z, s0.w, s1.x, s1.y, s1.z, s1.w};
        float tm = sv[0];
#pragma unroll
        for (int j = 1; j < 8; ++j) tm = fmaxf(tm, sv[j]);
        tm = fmaxf(tm, __shfl_xor(tm, 16));
        tm = fmaxf(tm, __shfl_xor(tm, 32));
        float nm = fmaxf(mrun, tm);
        float alpha = __expf(mrun - nm);
        float p[8];
        float rs = 0.f;
#pragma unroll
        for (int j = 0; j < 8; ++j) {
            p[j] = __expf(sv[j] - nm);
            rs += p[j];
        }
        rs += __shfl_xor(rs, 16);
        rs += __shfl_xor(rs, 32);
        lsum = lsum * alpha + rs;
        mrun = nm;
        o0.x *= alpha; o0.y *= alpha; o0.z *= alpha; o0.w *= alpha;
        o1.x *= alpha; o1.y *= alpha; o1.z *= alpha; o1.w *= alpha;

        // P -> fp16 hi/lo, transpose via per-wave LDS round-trip
        f16x4 ph0, pl0, ph1, pl1;
#pragma unroll
        for (int j = 0; j < 4; ++j) {
            _Float16 hi = (_Float16)p[j];
            ph0[j] = hi; pl0[j] = (_Float16)(p[j] - (float)hi);
            _Float16 hi1 = (_Float16)p[4 + j];
            ph1[j] = hi1; pl1[j] = (_Float16)(p[4 + j] - (float)hi1);
        }
        *(f16x4*)&sPhi[w][col * PROW + quad * 4] = ph0;
        *(f16x4*)&sPhi[w][col * PROW + 16 + quad * 4] = ph1;
        *(f16x4*)&sPlo[w][col * PROW + quad * 4] = pl0;
        *(f16x4*)&sPlo[w][col * PROW + 16 + quad * 4] = pl1;
        __asm__ volatile("s_waitcnt lgkmcnt(0)" ::: "memory");
        f16x8 pH = *(const f16x8*)&sPhi[w][col * PROW + quad * 8];
        f16x8 pL = *(const f16x8*)&sPlo[w][col * PROW + quad * 8];

        // PV: O^T += V^T · P^T  (two d-halves)
        f16x8 vh0 = *(const f16x8*)&sVhi[col * PROW + quad * 8];
        f16x8 vl0 = *(const f16x8*)&sVlo[col * PROW + quad * 8];
        f16x8 vh1 = *(const f16x8*)&sVhi[(16 + col) * PROW + quad * 8];
        f16x8 vl1 = *(const f16x8*)&sVlo[(16 + col) * PROW + quad * 8];
        o0 = __builtin_amdgcn_mfma_f32_16x16x32_f16(vh0, pH, o0, 0, 0, 0);
        o0 = __builtin_amdgcn_mfma_f32_16x16x32_f16(vh0, pL, o0, 0, 0, 0);
        o0 = __builtin_amdgcn_mfma_f32_16x16x32_f16(vl0, pH, o0, 0, 0, 0);
        o1 = __builtin_amdgcn_mfma_f32_16x16x32_f16(vh1, pH, o1, 0, 0, 0);
        o1 = __builtin_amdgcn_mfma_f32_16x16x32_f16(vh1, pL, o1, 0, 0, 0);
        o1 = __builtin_amdgcn_mfma_f32_16x16x32_f16(vl1, pH, o1, 0, 0, 0);
    }

    float inv = 1.f / lsum;
    // O^T C-layout: col=lane&15 = query, row = quad*4+reg = d (per half)
    float* op = O + ((size_t)(b * NN + q0 + col)) * CC + h * DH;
    float4 r0, r1;
    r0.x = o0.x * inv; r0.y = o0.y * inv; r0.z = o0.z * inv; r0.w = o0.w * inv;
    r1.x = o1.x * inv; r1.y = o1.y * inv; r1.z = o1.z * inv; r1.w = o1.w * inv;
    *(float4*)(op + quad * 4) = r0;
    *(float4*)(op + 16 + quad * 4) = r1;
}

// ---------------------------------------------------------------------------
// X = LayerNorm(X + P) per row of 256. One wave per row, 4 rows per block.
__global__ __launch_bounds__(256) void add_ln_k(float* __restrict__ X,
                                                const float* __restrict__ P,
                                                const float* __restrict__ g,
                                                const float* __restrict__ bta) {
    int wave = threadIdx.x >> 6, lane = threadIdx.x & 63;
    size_t row = (size_t)blockIdx.x * 4 + wave;
    float4 x = *(float4*)(X + row * CC + lane * 4);
    float4 p = *(const float4*)(P + row * CC + lane * 4);
    x.x += p.x; x.y += p.y; x.z += p.z; x.w += p.w;
    float sum = x.x + x.y + x.z + x.w;
    float ss = x.x * x.x + x.y * x.y + x.z * x.z + x.w * x.w;
#pragma unroll
    for (int off = 32; off; off >>= 1) {
        sum += __shfl_down(sum, off);
        ss += __shfl_down(ss, off);
    }
    sum = __shfl(sum, 0);
    ss = __shfl(ss, 0);
    float mean = sum * (1.f / 256.f);
    float var = ss * (1.f / 256.f) - mean * mean;
    float w = rsqrtf(var + EPSV);
    float4 gg = *(const float4*)(g + lane * 4);
    float4 bb = *(const float4*)(bta + lane * 4);
    x.x = (x.x - mean) * w * gg.x + bb.x;
    x.y = (x.y - mean) * w * gg.y + bb.y;
    x.z = (x.z - mean) * w * gg.z + bb.z;
    x.w = (x.w - mean) * w * gg.w + bb.w;
    *(float4*)(X + row * CC + lane * 4) = x;
}

// ---------------------------------------------------------------------------
__global__ __launch_bounds__(256) void bn_stats_k(const float* __restrict__ Hm,
                                                  float* __restrict__ stats,
                                                  int M, int Cc) {
    int c = blockIdx.x;
    int t = threadIdx.x;
    float s = 0.f, ss = 0.f;
    for (int r = t; r < M; r += 256) {
        float v = Hm[(size_t)r * Cc + c];
        s += v;
        ss += v * v;
    }
    __shared__ float sh0[256], sh1[256];
    sh0[t] = s; sh1[t] = ss;
    __syncthreads();
    for (int st = 128; st; st >>= 1) {
        if (t < st) { sh0[t] += sh0[t + st]; sh1[t] += sh1[t + st]; }
        __syncthreads();
    }
    if (t == 0) {
        float mean = sh0[0] / (float)M;
        stats[c] = mean;
        stats[Cc + c] = sh1[0] / (float)M - mean * mean;
    }
}

template <bool BIAS>
__global__ __launch_bounds__(256) void bn_apply_k(const float* __restrict__ in,
                                                  float* __restrict__ out,
                                                  const float* __restrict__ stats,
                                                  const float* __restrict__ gam,
                                                  const float* __restrict__ bet,
                                                  int total, int Cc, float alpha) {
    int i = blockIdx.x * 256 + threadIdx.x;
    if (i >= total) return;
    int c = i % Cc;
    float mean = stats[c], var = stats[Cc + c];
    float v = (in[i] - mean) * rsqrtf(var + EPSV) * gam[c] + bet[c];
    out[i] = v > 0.f ? v : alpha * v;
}

// ---------------------------------------------------------------------------
__global__ __launch_bounds__(64) void argmax_k(const float* __restrict__ H3,
                                               int* __restrict__ idxo,
                                               float* __restrict__ qpts,
                                               const float* __restrict__ pts) {
    int bc = blockIdx.x;
    int b = bc >> 4;
    int lane = threadIdx.x;
    float best = -1e30f;
    int bn = 0;
    for (int n = lane; n < NN; n += 64) {
        float v = H3[((size_t)(b * NN + n)) * 16 + (bc & 15)];
        if (v > best) { best = v; bn = n; }
    }
#pragma unroll
    for (int off = 32; off; off >>= 1) {
        float ov = __shfl_xor(best, off);
        int on = __shfl_xor(bn, off);
        if (ov > best || (ov == best && on < bn)) { best = ov; bn = on; }
    }
    if (lane == 0) idxo[bc] = bn;
    if (lane < 3) qpts[bc * 3 + lane] = pts[(size_t)b * 3 * NN + lane * NN + bn];
}

// ---------------------------------------------------------------------------
__global__ __launch_bounds__(64) void ball_k(const float* __restrict__ pts,
                                             const float* __restrict__ qpts,
                                             int* __restrict__ gi) {
    int bs = blockIdx.x;
    int b = bs >> 4;
    int lane = threadIdx.x;
    float qx = qpts[bs * 3], qy = qpts[bs * 3 + 1], qz = qpts[bs * 3 + 2];
    float qq = (qx * qx + qy * qy) + qz * qz;
    const float* px = pts + (size_t)b * 3 * NN;
    const float R2 = 0.09f;
    int cnt = 0;
    for (int base = 0; base < NN && cnt < NSAMPLE; base += 64) {
        int n = base + lane;
        float x = px[n], y = px[NN + n], z = px[2 * NN + n];
        float pp = (x * x + y * y) + z * z;
        float dot = (qx * x + qy * y) + qz * z;
        float sqd = (qq + pp) - 2.f * dot;
        bool ok = !(sqd > R2);
        unsigned long long mk = __ballot(ok);
        int pos = cnt + (int)__popcll(mk & ((1ull << lane) - 1ull));
        if (ok && pos < NSAMPLE) gi[bs * NSAMPLE + pos] = n;
        cnt += (int)__popcll(mk);
    }
    __syncthreads();
    int g0 = gi[bs * NSAMPLE];
    if (lane >= cnt && lane < NSAMPLE) gi[bs * NSAMPLE + lane] = g0;
}

// ---------------------------------------------------------------------------
__global__ __launch_bounds__(256) void gather_k(const float* __restrict__ pts,
                                                const float* __restrict__ qpts,
                                                const int* __restrict__ gi,
                                                float* __restrict__ G0) {
    int e = blockIdx.x * 256 + threadIdx.x;
    if (e >= BB * SS * KK * 3) return;
    int r = e / 3, d = e % 3;
    int k = r % KK;
    int bs = r / KK;
    int b = bs >> 4;
    float v;
    if (k == 0)
        v = qpts[bs * 3 + d];
    else
        v = pts[(size_t)b * 3 * NN + d * NN + gi[bs * NSAMPLE + k - 1]];
    G0[e] = v;
}

// ---------------------------------------------------------------------------
__global__ __launch_bounds__(256) void maxpool_k(const float* __restrict__ G3,
                                                 float* __restrict__ out) {
    int i = blockIdx.x * 256 + threadIdx.x;
    if (i >= BB * 512 * SS) return;
    int o = i & 511;
    int s = (i >> 9) & 15;
    int b = i >> 13;
    const float* p = G3 + ((size_t)(b * SS + s) * KK) * 512 + o;
    float mx = p[0];
#pragma unroll
    for (int k = 1; k < KK; ++k) mx = fmaxf(mx, p[(size_t)k * 512]);
    out[((size_t)(b * 512 + o)) * SS + s] = mx;
}

// ---------------------------------------------------------------------------
extern "C" void kernel_launch(void* const* d_in, const int* in_sizes, int n_in,
                              void* d_out, int out_size, void* d_ws, size_t ws_size,
                              hipStream_t stream) {
    const float* hoch = (const float*)d_in[0];
    const float* pts = (const float*)d_in[1];
    const float* Wq = (const float*)d_in[2];
    const float* Wk = (const float*)d_in[3];
    const float* Wv = (const float*)d_in[4];
    const float* Wo = (const float*)d_in[5];
    const float* ln_g = (const float*)d_in[6];
    const float* ln_b = (const float*)d_in[7];
    const float* fg_w1 = (const float*)d_in[8];
    const float* fg_b1 = (const float*)d_in[9];
    const float* fg_w2 = (const float*)d_in[10];
    const float* fg_b2 = (const float*)d_in[11];
    const float* fg_w3 = (const float*)d_in[12];
    const float* fg_b3 = (const float*)d_in[13];
    const float* fg_g1 = (const float*)d_in[14];
    const float* fg_be1 = (const float*)d_in[15];
    const float* fg_g2 = (const float*)d_in[16];
    const float* fg_be2 = (const float*)d_in[17];
    const float* fg_g3 = (const float*)d_in[18];
    const float* fg_be3 = (const float*)d_in[19];
    const float* cw1 = (const float*)d_in[20];
    const float* cw2 = (const float*)d_in[21];
    const float* cw3 = (const float*)d_in[22];
    const float* cg1 = (const float*)d_in[23];
    const float* cb1 = (const float*)d_in[24];
    const float* cg2 = (const float*)d_in[25];
    const float* cb2 = (const float*)d_in[26];
    const float* cg3 = (const float*)d_in[27];
    const float* cb3 = (const float*)d_in[28];
    float* out = (float*)d_out;

    float* ws = (float*)d_ws;
    const size_t MSZ = (size_t)BB * NN * CC;
    float* X = ws;
    float* bA = ws + MSZ;
    float* bB = ws + 2 * MSZ;
    float* bC = ws + 3 * MSZ;
    float* bD = ws + 4 * MSZ;
    float* sm = ws + 5 * MSZ;
    float* stats = sm;
    float* qpts = sm + 1024;
    int* idx = (int*)(sm + 1536);
    int* gi = (int*)(sm + 1664);
    float* G0 = sm + 4096;

    transpose_k<<<dim3(NN / 32, CC / 32, BB), dim3(32, 8), 0, stream>>>(hoch, X, CC, NN);

    const int Mrows = BB * NN;
    dim3 gProj(CC / 64, Mrows / 64);
    for (int l = 0; l < LL; ++l) {
        const float* wq = Wq + (size_t)l * CC * CC;
        const float* wk = Wk + (size_t)l * CC * CC;
        const float* wv = Wv + (size_t)l * CC * CC;
        const float* wo = Wo + (size_t)l * CC * CC;
        gemm_k<false, false><<<gProj, 256, 0, stream>>>(X, wq, nullptr, bA, Mrows, CC, CC);
        gemm_k<false, false><<<gProj, 256, 0, stream>>>(X, wk, nullptr, bB, Mrows, CC, CC);
        gemm_k<false, false><<<gProj, 256, 0, stream>>>(X, wv, nullptr, bC, Mrows, CC, CC);
        attn_mfma<<<dim3(NN / 64, BB * HH), 256, 0, stream>>>(bA, bB, bC, bD);
        gemm_k<false, false><<<gProj, 256, 0, stream>>>(bD, wo, nullptr, bA, Mrows, CC, CC);
        add_ln_k<<<Mrows / 4, 256, 0, stream>>>(X, bA, ln_g + l * CC, ln_b + l * CC);
    }

    gemm_k<true, true><<<dim3(1, Mrows / 64), 256, 0, stream>>>(X, fg_w1, fg_b1, bA, Mrows, 64, 256);
    bn_stats_k<<<64, 256, 0, stream>>>(bA, stats, Mrows, 64);
    bn_apply_k<true><<<(Mrows * 64 + 255) / 256, 256, 0, stream>>>(bA, bA, stats, fg_g1, fg_be1, Mrows * 64, 64, 0.f);
    gemm_k<true, true><<<dim3(1, Mrows / 64), 256, 0, stream>>>(bA, fg_w2, fg_b2, bB, Mrows, 32, 64);
    bn_stats_k<<<32, 256, 0, stream>>>(bB, stats, Mrows, 32);
    bn_apply_k<true><<<(Mrows * 32 + 255) / 256, 256, 0, stream>>>(bB, bB, stats, fg_g2, fg_be2, Mrows * 32, 32, 0.f);
    gemm_k<true, true><<<dim3(1, Mrows / 64), 256, 0, stream>>>(bB, fg_w3, fg_b3, bC, Mrows, 16, 32);
    bn_stats_k<<<16, 256, 0, stream>>>(bC, stats, Mrows, 16);
    bn_apply_k<true><<<(Mrows * 16 + 255) / 256, 256, 0, stream>>>(bC, bC, stats, fg_g3, fg_be3, Mrows * 16, 16, 0.f);

    argmax_k<<<BB * SS, 64, 0, stream>>>(bC, idx, qpts, pts);
    ball_k<<<BB * SS, 64, 0, stream>>>(pts, qpts, gi);
    gather_k<<<(BB * SS * KK * 3 + 255) / 256, 256, 0, stream>>>(pts, qpts, gi, G0);

    const int Mg = BB * SS * KK;
    gemm_k<true, false><<<dim3(1, Mg / 64), 256, 0, stream>>>(G0, cw1, nullptr, bA, Mg, 64, 3);
    bn_stats_k<<<64, 256, 0, stream>>>(bA, stats, Mg, 64);
    bn_apply_k<false><<<(Mg * 64 + 255) / 256, 256, 0, stream>>>(bA, bA, stats, cg1, cb1, Mg * 64, 64, 0.2f);
    gemm_k<true, false><<<dim3(4, Mg / 64), 256, 0, stream>>>(bA, cw2, nullptr, bB, Mg, 256, 64);
    bn_stats_k<<<256, 256, 0, stream>>>(bB, stats, Mg, 256);
    bn_apply_k<false><<<(Mg * 256 + 255) / 256, 256, 0, stream>>>(bB, bB, stats, cg2, cb2, Mg * 256, 256, 0.2f);
    gemm_k<true, false><<<dim3(8, Mg / 64), 256, 0, stream>>>(bB, cw3, nullptr, bC, Mg, 512, 256);
    bn_stats_k<<<512, 256, 0, stream>>>(bC, stats, Mg, 512);
    bn_apply_k<false><<<(Mg * 512 + 255) / 256, 256, 0, stream>>>(bC, bC, stats, cg3, cb3, Mg * 512, 512, 0.2f);

    maxpool_k<<<(BB * 512 * SS + 255) / 256, 256, 0, stream>>>(bC, out);

    (void)in_sizes; (void)n_in; (void)out_size; (void)ws_size; (void)idx;
}

// Round 4
// 560.180 us; speedup vs baseline: 4.4275x; 1.5767x over previous
//
#include <hip/hip_runtime.h>
#include <hip/hip_bf16.h>
#include <math.h>

// Problem constants
#define BB 4
#define NN 2048
#define CC 256
#define HH 8
#define DH 32
#define LL 2
#define SS 16          // number of selected points (B x 16 channels argmax)
#define KK 33          // 1 + NSAMPLE
#define NSAMPLE 32
#define EPSV 1e-5f

typedef _Float16 f16x8 __attribute__((ext_vector_type(8)));
typedef _Float16 f16x4 __attribute__((ext_vector_type(4)));
typedef float f32x4 __attribute__((ext_vector_type(4)));

struct hl16 { _Float16 h, l; };
__device__ __forceinline__ hl16 split2(float v) {
    hl16 r;
    r.h = (_Float16)v;
    r.l = (_Float16)(v - (float)r.h);
    return r;
}

// ---------------------------------------------------------------------------
// Transpose per batch: in (R x Ccols) -> out (Ccols x R)
__global__ __launch_bounds__(256) void transpose_k(const float* __restrict__ in,
                                                   float* __restrict__ out,
                                                   int R, int Ccols) {
    __shared__ float t[32][33];
    int n0 = blockIdx.x * 32, c0 = blockIdx.y * 32, b = blockIdx.z;
    const float* ip = in + (size_t)b * R * Ccols;
    float* op = out + (size_t)b * R * Ccols;
    int tx = threadIdx.x, ty = threadIdx.y;
#pragma unroll
    for (int i = 0; i < 4; ++i)
        t[ty + i * 8][tx] = ip[(size_t)(c0 + ty + i * 8) * Ccols + n0 + tx];
    __syncthreads();
#pragma unroll
    for (int i = 0; i < 4; ++i)
        op[(size_t)(n0 + ty + i * 8) * R + c0 + tx] = t[tx][ty + i * 8];
}

// ---------------------------------------------------------------------------
// Generic fp32 GEMM (small shapes: fg2, fg3, cw1)
template <bool TRANSB, bool BIAS>
__global__ __launch_bounds__(256) void gemm_k(const float* __restrict__ A,
                                              const float* __restrict__ Bm,
                                              const float* __restrict__ bias,
                                              float* __restrict__ Cm,
                                              int M, int Nc, int K) {
    __shared__ float As[16][68];
    __shared__ float Bs[16][68];
    int t = threadIdx.x;
    int tx = t & 15, ty = t >> 4;
    int row0 = blockIdx.y * 64, col0 = blockIdx.x * 64;
    float acc[4][4] = {};
    for (int k0 = 0; k0 < K; k0 += 16) {
#pragma unroll
        for (int p = 0; p < 4; ++p) {
            int i = t + 256 * p;
            int m = i >> 4, k = i & 15;
            int gm = row0 + m, gk = k0 + k;
            As[k][m] = (gm < M && gk < K) ? A[(size_t)gm * K + gk] : 0.f;
        }
#pragma unroll
        for (int p = 0; p < 4; ++p) {
            int i = t + 256 * p;
            if (TRANSB) {
                int k = i & 15, n = i >> 4;
                int gn = col0 + n, gk = k0 + k;
                Bs[k][n] = (gn < Nc && gk < K) ? Bm[(size_t)gn * K + gk] : 0.f;
            } else {
                int n = i & 63, k = i >> 6;
                int gn = col0 + n, gk = k0 + k;
                Bs[k][n] = (gn < Nc && gk < K) ? Bm[(size_t)gk * Nc + gn] : 0.f;
            }
        }
        __syncthreads();
#pragma unroll
        for (int kk = 0; kk < 16; ++kk) {
            float4 a4 = *(const float4*)&As[kk][ty * 4];
            float4 b4 = *(const float4*)&Bs[kk][tx * 4];
            float av[4] = {a4.x, a4.y, a4.z, a4.w};
            float bv[4] = {b4.x, b4.y, b4.z, b4.w};
#pragma unroll
            for (int i = 0; i < 4; ++i)
#pragma unroll
                for (int j = 0; j < 4; ++j) acc[i][j] = fmaf(av[i], bv[j], acc[i][j]);
        }
        __syncthreads();
    }
#pragma unroll
    for (int i = 0; i < 4; ++i) {
        int r = row0 + ty * 4 + i;
        if (r >= M) continue;
#pragma unroll
        for (int j = 0; j < 4; ++j) {
            int c = col0 + tx * 4 + j;
            if (c >= Nc) continue;
            float v = acc[i][j];
            if (BIAS) v += bias[c];
            Cm[(size_t)r * Nc + c] = v;
        }
    }
}

// ---------------------------------------------------------------------------
// Split-fp16 MFMA GEMM body. C = A*B (+bias). A: fp32 [M][K]. B: fp32
// [N][K] (TRANSB) or [K][N]. fp32 out. Requires M%TM==0, Nc%64==0, K%32==0.
// Split precision: x=hi+lo fp16; C = Ah*Bh + Ah*Bl + Al*Bh (~2^-22 rel err).
template <int TM, bool TRANSB, bool BIAS>
__device__ __forceinline__ void gemm_sp_body(const float* __restrict__ A,
                                             const float* __restrict__ Bm,
                                             const float* __restrict__ bias,
                                             float* __restrict__ Cm,
                                             int Nc, int K, int row0, int col0,
                                             _Float16* __restrict__ sAh, _Float16* __restrict__ sAl,
                                             _Float16* __restrict__ sBh, _Float16* __restrict__ sBl,
                                             float* __restrict__ sTmp) {
    int t = threadIdx.x, w = t >> 6, lane = t & 63;
    int col = lane & 15, quad = lane >> 4;
    const int m0w = (TM == 128) ? (w & 1) * 64 : 0;
    const int n0w = (TM == 128) ? (w >> 1) * 32 : w * 16;
    constexpr int NT = (TM == 128) ? 2 : 1;
    f32x4 acc[4][NT];
#pragma unroll
    for (int i = 0; i < 4; ++i)
#pragma unroll
        for (int j = 0; j < NT; ++j) acc[i][j] = (f32x4){0.f, 0.f, 0.f, 0.f};

    for (int k0 = 0; k0 < K; k0 += 32) {
        __syncthreads();  // previous tile fully consumed
        // ---- stage A (convert to hi/lo) ----
#pragma unroll
        for (int c = 0; c < TM / 32; ++c) {
            int idx4 = t + 256 * c;
            int r = idx4 >> 3, dc = (idx4 & 7) * 4;
            float4 a = *(const float4*)(A + (size_t)(row0 + r) * K + k0 + dc);
            float av[4] = {a.x, a.y, a.z, a.w};
            f16x4 h4, l4;
#pragma unroll
            for (int j = 0; j < 4; ++j) {
                hl16 s = split2(av[j]);
                h4[j] = s.h; l4[j] = s.l;
            }
            *(f16x4*)&sAh[r * 40 + dc] = h4;
            *(f16x4*)&sAl[r * 40 + dc] = l4;
        }
        // ---- stage B ----
        if constexpr (TRANSB) {
#pragma unroll
            for (int c = 0; c < 2; ++c) {
                int idx4 = t + 256 * c;
                int n = idx4 >> 3, dc = (idx4 & 7) * 4;
                float4 bq = *(const float4*)(Bm + (size_t)(col0 + n) * K + k0 + dc);
                float bv[4] = {bq.x, bq.y, bq.z, bq.w};
                f16x4 h4, l4;
#pragma unroll
                for (int j = 0; j < 4; ++j) {
                    hl16 s = split2(bv[j]);
                    h4[j] = s.h; l4[j] = s.l;
                }
                *(f16x4*)&sBh[n * 40 + dc] = h4;
                *(f16x4*)&sBl[n * 40 + dc] = l4;
            }
        } else {
            // B is [K][N]: stage raw coalesced, then transpose+convert
#pragma unroll
            for (int c = 0; c < 2; ++c) {
                int idx4 = t + 256 * c;
                int k = idx4 >> 4, nc4 = (idx4 & 15) * 4;
                *(float4*)&sTmp[k * 68 + nc4] =
                    *(const float4*)(Bm + (size_t)(k0 + k) * Nc + col0 + nc4);
            }
            __syncthreads();
            {
                int n = t & 63, kb = (t >> 6) * 8;
                f16x4 h0, l0, h1, l1;
#pragma unroll
                for (int j = 0; j < 4; ++j) {
                    hl16 s0 = split2(sTmp[(kb + j) * 68 + n]);
                    h0[j] = s0.h; l0[j] = s0.l;
                    hl16 s1 = split2(sTmp[(kb + 4 + j) * 68 + n]);
                    h1[j] = s1.h; l1[j] = s1.l;
                }
                *(f16x4*)&sBh[n * 40 + kb] = h0;
                *(f16x4*)&sBh[n * 40 + kb + 4] = h1;
                *(f16x4*)&sBl[n * 40 + kb] = l0;
                *(f16x4*)&sBl[n * 40 + kb + 4] = l1;
            }
        }
        __syncthreads();
        // ---- fragments + MFMA ----
        f16x8 ah[4], al[4], bh[NT], bl[NT];
#pragma unroll
        for (int i = 0; i < 4; ++i) {
            ah[i] = *(const f16x8*)&sAh[(m0w + i * 16 + col) * 40 + quad * 8];
            al[i] = *(const f16x8*)&sAl[(m0w + i * 16 + col) * 40 + quad * 8];
        }
#pragma unroll
        for (int j = 0; j < NT; ++j) {
            bh[j] = *(const f16x8*)&sBh[(n0w + j * 16 + col) * 40 + quad * 8];
            bl[j] = *(const f16x8*)&sBl[(n0w + j * 16 + col) * 40 + quad * 8];
        }
#pragma unroll
        for (int i = 0; i < 4; ++i)
#pragma unroll
            for (int j = 0; j < NT; ++j) {
                acc[i][j] = __builtin_amdgcn_mfma_f32_16x16x32_f16(ah[i], bh[j], acc[i][j], 0, 0, 0);
                acc[i][j] = __builtin_amdgcn_mfma_f32_16x16x32_f16(ah[i], bl[j], acc[i][j], 0, 0, 0);
                acc[i][j] = __builtin_amdgcn_mfma_f32_16x16x32_f16(al[i], bh[j], acc[i][j], 0, 0, 0);
            }
    }
    // ---- epilogue: D col=lane&15 -> n, row=quad*4+reg -> m ----
#pragma unroll
    for (int i = 0; i < 4; ++i)
#pragma unroll
        for (int j = 0; j < NT; ++j) {
            int n = col0 + n0w + j * 16 + col;
            float bv = BIAS ? bias[n] : 0.f;
#pragma unroll
            for (int r = 0; r < 4; ++r) {
                int m = row0 + m0w + i * 16 + quad * 4 + r;
                Cm[(size_t)m * Nc + n] = acc[i][j][r] + bv;
            }
        }
}

template <int TM, bool TRANSB, bool BIAS>
__global__ __launch_bounds__(256) void gemm_sp(const float* __restrict__ A,
                                               const float* __restrict__ Bm,
                                               const float* __restrict__ bias,
                                               float* __restrict__ Cm,
                                               int Nc, int K) {
    __shared__ _Float16 sAh[TM * 40], sAl[TM * 40];
    __shared__ _Float16 sBh[64 * 40], sBl[64 * 40];
    __shared__ float sTmp[TRANSB ? 4 : 32 * 68];
    gemm_sp_body<TM, TRANSB, BIAS>(A, Bm, bias, Cm, Nc, K, blockIdx.y * TM,
                                   blockIdx.x * 64, sAh, sAl, sBh, sBl, sTmp);
}

// Fused QKV: blockIdx.x in [0,12): matrix = x>>2, col block = x&3.
__global__ __launch_bounds__(256) void gemm_qkv(const float* __restrict__ X,
                                                const float* __restrict__ Wq,
                                                const float* __restrict__ Wk,
                                                const float* __restrict__ Wv,
                                                float* __restrict__ Qo,
                                                float* __restrict__ Ko,
                                                float* __restrict__ Vo) {
    __shared__ _Float16 sAh[128 * 40], sAl[128 * 40];
    __shared__ _Float16 sBh[64 * 40], sBl[64 * 40];
    __shared__ float sTmp[32 * 68];
    int mat = blockIdx.x >> 2;
    const float* Bm = mat == 0 ? Wq : (mat == 1 ? Wk : Wv);
    float* Cm = mat == 0 ? Qo : (mat == 1 ? Ko : Vo);
    gemm_sp_body<128, false, false>(X, Bm, nullptr, Cm, CC, CC, blockIdx.y * 128,
                                    (blockIdx.x & 3) * 64, sAh, sAl, sBh, sBl, sTmp);
}

// ---------------------------------------------------------------------------
// Split-fp16 MFMA flash attention, 128 queries/block (32 per wave, 2 q-tiles).
#define PK 40    // K & P row pad (fp16 units) -> 80B rows, 16B aligned
#define PVQ 36   // V^T row pad -> 72B rows, 8B aligned (b64 frag reads)
__global__ __launch_bounds__(256) void attn_mfma(const float* __restrict__ Q,
                                                 const float* __restrict__ Kg,
                                                 const float* __restrict__ Vg,
                                                 float* __restrict__ O) {
    __shared__ _Float16 sKh[32 * PK], sKl[32 * PK];
    __shared__ _Float16 sVh[32 * PVQ], sVl[32 * PVQ];
    __shared__ _Float16 sPh[8][16 * PK], sPl[8][16 * PK];

    int t = threadIdx.x, w = t >> 6, lane = t & 63;
    int col = lane & 15, quad = lane >> 4;
    int bh = blockIdx.y, b = bh >> 3, h = bh & 7;
    int qbase = blockIdx.x * 128 + w * 32;
    const float scale = 0.17677669529663687f;  // 1/sqrt(32)

    // Q fragments (B-operand layout), split hi/lo (scale applied to S later)
    f16x8 qh[2], ql[2];
#pragma unroll
    for (int qt = 0; qt < 2; ++qt) {
        const float* qp = Q + ((size_t)(b * NN + qbase + qt * 16 + col)) * CC + h * DH + quad * 8;
        float4 qa = *(const float4*)qp;
        float4 qb = *(const float4*)(qp + 4);
        float qv[8] = {qa.x, qa.y, qa.z, qa.w, qb.x, qb.y, qb.z, qb.w};
#pragma unroll
        for (int j = 0; j < 8; ++j) {
            hl16 s = split2(qv[j]);
            qh[qt][j] = s.h; ql[qt][j] = s.l;
        }
    }

    f32x4 o[2][2];
#pragma unroll
    for (int a = 0; a < 2; ++a)
#pragma unroll
        for (int d = 0; d < 2; ++d) o[a][d] = (f32x4){0.f, 0.f, 0.f, 0.f};
    float mrun[2] = {-1e30f, -1e30f}, lsum[2] = {0.f, 0.f};

    int skey = t >> 3, sd = (t & 7) * 4;       // K staging: [key][d]
    int vd = t & 31, vkb = (t >> 5) * 4;       // V staging: d-major
    const float* Kbase = Kg + ((size_t)(b * NN)) * CC + h * DH;
    const float* Vbase = Vg + ((size_t)(b * NN)) * CC + h * DH;

    for (int k0 = 0; k0 < NN; k0 += 32) {
        float4 kf = *(const float4*)(Kbase + (size_t)(k0 + skey) * CC + sd);
        float vf[4];
#pragma unroll
        for (int j = 0; j < 4; ++j)
            vf[j] = Vbase[(size_t)(k0 + vkb + j) * CC + vd];
        __syncthreads();  // previous tile fully consumed
        {
            float kv[4] = {kf.x, kf.y, kf.z, kf.w};
            f16x4 h4, l4;
#pragma unroll
            for (int j = 0; j < 4; ++j) {
                hl16 s = split2(kv[j]);
                h4[j] = s.h; l4[j] = s.l;
            }
            *(f16x4*)&sKh[skey * PK + sd] = h4;
            *(f16x4*)&sKl[skey * PK + sd] = l4;
            f16x4 vh4, vl4;
#pragma unroll
            for (int j = 0; j < 4; ++j) {
                hl16 s = split2(vf[j]);
                vh4[j] = s.h; vl4[j] = s.l;
            }
            *(f16x4*)&sVh[vd * PVQ + vkb] = vh4;  // transposed: [d][key]
            *(f16x4*)&sVl[vd * PVQ + vkb] = vl4;
        }
        __syncthreads();

        // ---- QK^T (S^T = K·Q^T): key subtiles kt, query tiles qt ----
        f32x4 s[2][2];
#pragma unroll
        for (int kt = 0; kt < 2; ++kt) {
            f16x8 kh = *(const f16x8*)&sKh[(kt * 16 + col) * PK + quad * 8];
            f16x8 kl = *(const f16x8*)&sKl[(kt * 16 + col) * PK + quad * 8];
#pragma unroll
            for (int qt = 0; qt < 2; ++qt) {
                f32x4 z = {0.f, 0.f, 0.f, 0.f};
                z = __builtin_amdgcn_mfma_f32_16x16x32_f16(kh, qh[qt], z, 0, 0, 0);
                z = __builtin_amdgcn_mfma_f32_16x16x32_f16(kh, ql[qt], z, 0, 0, 0);
                z = __builtin_amdgcn_mfma_f32_16x16x32_f16(kl, qh[qt], z, 0, 0, 0);
                s[kt][qt] = z;
            }
        }

        // ---- online softmax + P split/write (per q-tile) ----
#pragma unroll
        for (int qt = 0; qt < 2; ++qt) {
            float sv[8];
#pragma unroll
            for (int j = 0; j < 4; ++j) {
                sv[j] = s[0][qt][j] * scale;
                sv[4 + j] = s[1][qt][j] * scale;
            }
            float tm = sv[0];
#pragma unroll
            for (int j = 1; j < 8; ++j) tm = fmaxf(tm, sv[j]);
            tm = fmaxf(tm, __shfl_xor(tm, 16));
            tm = fmaxf(tm, __shfl_xor(tm, 32));
            float nm = fmaxf(mrun[qt], tm);
            float alpha = __expf(mrun[qt] - nm);
            float p[8], rs = 0.f;
#pragma unroll
            for (int j = 0; j < 8; ++j) {
                p[j] = __expf(sv[j] - nm);
                rs += p[j];
            }
            rs += __shfl_xor(rs, 16);
            rs += __shfl_xor(rs, 32);
            lsum[qt] = lsum[qt] * alpha + rs;
            mrun[qt] = nm;
#pragma unroll
            for (int d = 0; d < 2; ++d) {
                o[qt][d].x *= alpha; o[qt][d].y *= alpha;
                o[qt][d].z *= alpha; o[qt][d].w *= alpha;
            }
            f16x4 ph0, pl0, ph1, pl1;
#pragma unroll
            for (int j = 0; j < 4; ++j) {
                hl16 s0 = split2(p[j]);
                ph0[j] = s0.h; pl0[j] = s0.l;
                hl16 s1 = split2(p[4 + j]);
                ph1[j] = s1.h; pl1[j] = s1.l;
            }
            int reg = w * 2 + qt;
            *(f16x4*)&sPh[reg][col * PK + quad * 4] = ph0;
            *(f16x4*)&sPh[reg][col * PK + 16 + quad * 4] = ph1;
            *(f16x4*)&sPl[reg][col * PK + quad * 4] = pl0;
            *(f16x4*)&sPl[reg][col * PK + 16 + quad * 4] = pl1;
        }
        __asm__ volatile("s_waitcnt lgkmcnt(0)" ::: "memory");
        f16x8 pH[2], pL[2];
#pragma unroll
        for (int qt = 0; qt < 2; ++qt) {
            int reg = w * 2 + qt;
            pH[qt] = *(const f16x8*)&sPh[reg][col * PK + quad * 8];
            pL[qt] = *(const f16x8*)&sPl[reg][col * PK + quad * 8];
        }

        // ---- PV: O^T += V^T · P^T (two d-halves) ----
#pragma unroll
        for (int d = 0; d < 2; ++d) {
            f16x4 va = *(const f16x4*)&sVh[(d * 16 + col) * PVQ + quad * 8];
            f16x4 vb = *(const f16x4*)&sVh[(d * 16 + col) * PVQ + quad * 8 + 4];
            f16x8 vh = __builtin_shufflevector(va, vb, 0, 1, 2, 3, 4, 5, 6, 7);
            f16x4 vc = *(const f16x4*)&sVl[(d * 16 + col) * PVQ + quad * 8];
            f16x4 vdd = *(const f16x4*)&sVl[(d * 16 + col) * PVQ + quad * 8 + 4];
            f16x8 vl = __builtin_shufflevector(vc, vdd, 0, 1, 2, 3, 4, 5, 6, 7);
#pragma unroll
            for (int qt = 0; qt < 2; ++qt) {
                o[qt][d] = __builtin_amdgcn_mfma_f32_16x16x32_f16(vh, pH[qt], o[qt][d], 0, 0, 0);
                o[qt][d] = __builtin_amdgcn_mfma_f32_16x16x32_f16(vh, pL[qt], o[qt][d], 0, 0, 0);
                o[qt][d] = __builtin_amdgcn_mfma_f32_16x16x32_f16(vl, pH[qt], o[qt][d], 0, 0, 0);
            }
        }
    }

    // ---- epilogue: O^T layout col=q, row=d ----
#pragma unroll
    for (int qt = 0; qt < 2; ++qt) {
        float inv = 1.f / lsum[qt];
        float* op = O + ((size_t)(b * NN + qbase + qt * 16 + col)) * CC + h * DH;
#pragma unroll
        for (int d = 0; d < 2; ++d) {
            float4 r;
            r.x = o[qt][d].x * inv; r.y = o[qt][d].y * inv;
            r.z = o[qt][d].z * inv; r.w = o[qt][d].w * inv;
            *(float4*)(op + d * 16 + quad * 4) = r;
        }
    }
}

// ---------------------------------------------------------------------------
// X = LayerNorm(X + P) per row of 256. One wave per row, 4 rows per block.
__global__ __launch_bounds__(256) void add_ln_k(float* __restrict__ X,
                                                const float* __restrict__ P,
                                                const float* __restrict__ g,
                                                const float* __restrict__ bta) {
    int wave = threadIdx.x >> 6, lane = threadIdx.x & 63;
    size_t row = (size_t)blockIdx.x * 4 + wave;
    float4 x = *(float4*)(X + row * CC + lane * 4);
    float4 p = *(const float4*)(P + row * CC + lane * 4);
    x.x += p.x; x.y += p.y; x.z += p.z; x.w += p.w;
    float sum = x.x + x.y + x.z + x.w;
    float ss = x.x * x.x + x.y * x.y + x.z * x.z + x.w * x.w;
#pragma unroll
    for (int off = 32; off; off >>= 1) {
        sum += __shfl_down(sum, off);
        ss += __shfl_down(ss, off);
    }
    sum = __shfl(sum, 0);
    ss = __shfl(ss, 0);
    float mean = sum * (1.f / 256.f);
    float var = ss * (1.f / 256.f) - mean * mean;
    float wn = rsqrtf(var + EPSV);
    float4 gg = *(const float4*)(g + lane * 4);
    float4 bb = *(const float4*)(bta + lane * 4);
    x.x = (x.x - mean) * wn * gg.x + bb.x;
    x.y = (x.y - mean) * wn * gg.y + bb.y;
    x.z = (x.z - mean) * wn * gg.z + bb.z;
    x.w = (x.w - mean) * wn * gg.w + bb.w;
    *(float4*)(X + row * CC + lane * 4) = x;
}

// ---------------------------------------------------------------------------
__global__ __launch_bounds__(256) void bn_stats_k(const float* __restrict__ Hm,
                                                  float* __restrict__ stats,
                                                  int M, int Cc) {
    int c = blockIdx.x;
    int t = threadIdx.x;
    float s = 0.f, ss = 0.f;
    for (int r = t; r < M; r += 256) {
        float v = Hm[(size_t)r * Cc + c];
        s += v;
        ss += v * v;
    }
    __shared__ float sh0[256], sh1[256];
    sh0[t] = s; sh1[t] = ss;
    __syncthreads();
    for (int st = 128; st; st >>= 1) {
        if (t < st) { sh0[t] += sh0[t + st]; sh1[t] += sh1[t + st]; }
        __syncthreads();
    }
    if (t == 0) {
        float mean = sh0[0] / (float)M;
        stats[c] = mean;
        stats[Cc + c] = sh1[0] / (float)M - mean * mean;
    }
}

template <bool BIAS>
__global__ __launch_bounds__(256) void bn_apply_k(const float* __restrict__ in,
                                                  float* __restrict__ out,
                                                  const float* __restrict__ stats,
                                                  const float* __restrict__ gam,
                                                  const float* __restrict__ bet,
                                                  int total, int Cc, float alpha) {
    int i = blockIdx.x * 256 + threadIdx.x;
    if (i >= total) return;
    int c = i % Cc;
    float mean = stats[c], var = stats[Cc + c];
    float v = (in[i] - mean) * rsqrtf(var + EPSV) * gam[c] + bet[c];
    out[i] = v > 0.f ? v : alpha * v;
}

// ---------------------------------------------------------------------------
__global__ __launch_bounds__(64) void argmax_k(const float* __restrict__ H3,
                                               int* __restrict__ idxo,
                                               float* __restrict__ qpts,
                                               const float* __restrict__ pts) {
    int bc = blockIdx.x;
    int b = bc >> 4;
    int lane = threadIdx.x;
    float best = -1e30f;
    int bn = 0;
    for (int n = lane; n < NN; n += 64) {
        float v = H3[((size_t)(b * NN + n)) * 16 + (bc & 15)];
        if (v > best) { best = v; bn = n; }
    }
#pragma unroll
    for (int off = 32; off; off >>= 1) {
        float ov = __shfl_xor(best, off);
        int on = __shfl_xor(bn, off);
        if (ov > best || (ov == best && on < bn)) { best = ov; bn = on; }
    }
    if (lane == 0) idxo[bc] = bn;
    if (lane < 3) qpts[bc * 3 + lane] = pts[(size_t)b * 3 * NN + lane * NN + bn];
}

// ---------------------------------------------------------------------------
__global__ __launch_bounds__(64) void ball_k(const float* __restrict__ pts,
                                             const float* __restrict__ qpts,
                                             int* __restrict__ gi) {
    int bs = blockIdx.x;
    int b = bs >> 4;
    int lane = threadIdx.x;
    float qx = qpts[bs * 3], qy = qpts[bs * 3 + 1], qz = qpts[bs * 3 + 2];
    float qq = (qx * qx + qy * qy) + qz * qz;
    const float* px = pts + (size_t)b * 3 * NN;
    const float R2 = 0.09f;
    int cnt = 0;
    for (int base = 0; base < NN && cnt < NSAMPLE; base += 64) {
        int n = base + lane;
        float x = px[n], y = px[NN + n], z = px[2 * NN + n];
        float pp = (x * x + y * y) + z * z;
        float dot = (qx * x + qy * y) + qz * z;
        float sqd = (qq + pp) - 2.f * dot;
        bool ok = !(sqd > R2);
        unsigned long long mk = __ballot(ok);
        int pos = cnt + (int)__popcll(mk & ((1ull << lane) - 1ull));
        if (ok && pos < NSAMPLE) gi[bs * NSAMPLE + pos] = n;
        cnt += (int)__popcll(mk);
    }
    __syncthreads();
    int g0 = gi[bs * NSAMPLE];
    if (lane >= cnt && lane < NSAMPLE) gi[bs * NSAMPLE + lane] = g0;
}

// ---------------------------------------------------------------------------
__global__ __launch_bounds__(256) void gather_k(const float* __restrict__ pts,
                                                const float* __restrict__ qpts,
                                                const int* __restrict__ gi,
                                                float* __restrict__ G0) {
    int e = blockIdx.x * 256 + threadIdx.x;
    if (e >= BB * SS * KK * 3) return;
    int r = e / 3, d = e % 3;
    int k = r % KK;
    int bs = r / KK;
    int b = bs >> 4;
    float v;
    if (k == 0)
        v = qpts[bs * 3 + d];
    else
        v = pts[(size_t)b * 3 * NN + d * NN + gi[bs * NSAMPLE + k - 1]];
    G0[e] = v;
}

// ---------------------------------------------------------------------------
__global__ __launch_bounds__(256) void maxpool_k(const float* __restrict__ G3,
                                                 float* __restrict__ out) {
    int i = blockIdx.x * 256 + threadIdx.x;
    if (i >= BB * 512 * SS) return;
    int o = i & 511;
    int s = (i >> 9) & 15;
    int b = i >> 13;
    const float* p = G3 + ((size_t)(b * SS + s) * KK) * 512 + o;
    float mx = p[0];
#pragma unroll
    for (int k = 1; k < KK; ++k) mx = fmaxf(mx, p[(size_t)k * 512]);
    out[((size_t)(b * 512 + o)) * SS + s] = mx;
}

// ---------------------------------------------------------------------------
extern "C" void kernel_launch(void* const* d_in, const int* in_sizes, int n_in,
                              void* d_out, int out_size, void* d_ws, size_t ws_size,
                              hipStream_t stream) {
    const float* hoch = (const float*)d_in[0];
    const float* pts = (const float*)d_in[1];
    const float* Wq = (const float*)d_in[2];
    const float* Wk = (const float*)d_in[3];
    const float* Wv = (const float*)d_in[4];
    const float* Wo = (const float*)d_in[5];
    const float* ln_g = (const float*)d_in[6];
    const float* ln_b = (const float*)d_in[7];
    const float* fg_w1 = (const float*)d_in[8];
    const float* fg_b1 = (const float*)d_in[9];
    const float* fg_w2 = (const float*)d_in[10];
    const float* fg_b2 = (const float*)d_in[11];
    const float* fg_w3 = (const float*)d_in[12];
    const float* fg_b3 = (const float*)d_in[13];
    const float* fg_g1 = (const float*)d_in[14];
    const float* fg_be1 = (const float*)d_in[15];
    const float* fg_g2 = (const float*)d_in[16];
    const float* fg_be2 = (const float*)d_in[17];
    const float* fg_g3 = (const float*)d_in[18];
    const float* fg_be3 = (const float*)d_in[19];
    const float* cw1 = (const float*)d_in[20];
    const float* cw2 = (const float*)d_in[21];
    const float* cw3 = (const float*)d_in[22];
    const float* cg1 = (const float*)d_in[23];
    const float* cb1 = (const float*)d_in[24];
    const float* cg2 = (const float*)d_in[25];
    const float* cb2 = (const float*)d_in[26];
    const float* cg3 = (const float*)d_in[27];
    const float* cb3 = (const float*)d_in[28];
    float* out = (float*)d_out;

    float* ws = (float*)d_ws;
    const size_t MSZ = (size_t)BB * NN * CC;
    float* X = ws;
    float* bA = ws + MSZ;
    float* bB = ws + 2 * MSZ;
    float* bC = ws + 3 * MSZ;
    float* bD = ws + 4 * MSZ;
    float* sm = ws + 5 * MSZ;
    float* stats = sm;
    float* qpts = sm + 1024;
    int* idx = (int*)(sm + 1536);
    int* gi = (int*)(sm + 1664);
    float* G0 = sm + 4096;

    transpose_k<<<dim3(NN / 32, CC / 32, BB), dim3(32, 8), 0, stream>>>(hoch, X, CC, NN);

    const int Mrows = BB * NN;
    for (int l = 0; l < LL; ++l) {
        const float* wq = Wq + (size_t)l * CC * CC;
        const float* wk = Wk + (size_t)l * CC * CC;
        const float* wv = Wv + (size_t)l * CC * CC;
        const float* wo = Wo + (size_t)l * CC * CC;
        gemm_qkv<<<dim3(12, Mrows / 128), 256, 0, stream>>>(X, wq, wk, wv, bA, bB, bC);
        attn_mfma<<<dim3(NN / 128, BB * HH), 256, 0, stream>>>(bA, bB, bC, bD);
        gemm_sp<128, false, false><<<dim3(CC / 64, Mrows / 128), 256, 0, stream>>>(bD, wo, nullptr, bA, CC, CC);
        add_ln_k<<<Mrows / 4, 256, 0, stream>>>(X, bA, ln_g + l * CC, ln_b + l * CC);
    }

    // fg head: 256 -> 64 -> 32 -> 16, BN+ReLU each
    gemm_sp<64, true, true><<<dim3(1, Mrows / 64), 256, 0, stream>>>(X, fg_w1, fg_b1, bA, 64, 256);
    bn_stats_k<<<64, 256, 0, stream>>>(bA, stats, Mrows, 64);
    bn_apply_k<true><<<(Mrows * 64 + 255) / 256, 256, 0, stream>>>(bA, bA, stats, fg_g1, fg_be1, Mrows * 64, 64, 0.f);
    gemm_k<true, true><<<dim3(1, Mrows / 64), 256, 0, stream>>>(bA, fg_w2, fg_b2, bB, Mrows, 32, 64);
    bn_stats_k<<<32, 256, 0, stream>>>(bB, stats, Mrows, 32);
    bn_apply_k<true><<<(Mrows * 32 + 255) / 256, 256, 0, stream>>>(bB, bB, stats, fg_g2, fg_be2, Mrows * 32, 32, 0.f);
    gemm_k<true, true><<<dim3(1, Mrows / 64), 256, 0, stream>>>(bB, fg_w3, fg_b3, bC, Mrows, 16, 32);
    bn_stats_k<<<16, 256, 0, stream>>>(bC, stats, Mrows, 16);
    bn_apply_k<true><<<(Mrows * 16 + 255) / 256, 256, 0, stream>>>(bC, bC, stats, fg_g3, fg_be3, Mrows * 16, 16, 0.f);

    argmax_k<<<BB * SS, 64, 0, stream>>>(bC, idx, qpts, pts);
    ball_k<<<BB * SS, 64, 0, stream>>>(pts, qpts, gi);
    gather_k<<<(BB * SS * KK * 3 + 255) / 256, 256, 0, stream>>>(pts, qpts, gi, G0);

    // conv stack: 3 -> 64 -> 256 -> 512, BN+LeakyReLU(0.2)
    const int Mg = BB * SS * KK;  // 2112 = 33*64
    gemm_k<true, false><<<dim3(1, Mg / 64), 256, 0, stream>>>(G0, cw1, nullptr, bA, Mg, 64, 3);
    bn_stats_k<<<64, 256, 0, stream>>>(bA, stats, Mg, 64);
    bn_apply_k<false><<<(Mg * 64 + 255) / 256, 256, 0, stream>>>(bA, bA, stats, cg1, cb1, Mg * 64, 64, 0.2f);
    gemm_sp<64, true, false><<<dim3(4, Mg / 64), 256, 0, stream>>>(bA, cw2, nullptr, bB, 256, 64);
    bn_stats_k<<<256, 256, 0, stream>>>(bB, stats, Mg, 256);
    bn_apply_k<false><<<(Mg * 256 + 255) / 256, 256, 0, stream>>>(bB, bB, stats, cg2, cb2, Mg * 256, 256, 0.2f);
    gemm_sp<64, true, false><<<dim3(8, Mg / 64), 256, 0, stream>>>(bB, cw3, nullptr, bC, 512, 256);
    bn_stats_k<<<512, 256, 0, stream>>>(bC, stats, Mg, 512);
    bn_apply_k<false><<<(Mg * 512 + 255) / 256, 256, 0, stream>>>(bC, bC, stats, cg3, cb3, Mg * 512, 512, 0.2f);

    maxpool_k<<<(BB * 512 * SS + 255) / 256, 256, 0, stream>>>(bC, out);

    (void)in_sizes; (void)n_in; (void)out_size; (void)ws_size; (void)idx;
}

// Round 5
// 542.063 us; speedup vs baseline: 4.5754x; 1.0334x over previous
//
#include <hip/hip_runtime.h>
#include <hip/hip_bf16.h>
#include <math.h>

// Problem constants
#define BB 4
#define NN 2048
#define CC 256
#define HH 8
#define DH 32
#define LL 2
#define SS 16
#define KK 33
#define NSAMPLE 32
#define EPSV 1e-5f

typedef _Float16 f16x8 __attribute__((ext_vector_type(8)));
typedef _Float16 f16x4 __attribute__((ext_vector_type(4)));
typedef float f32x4 __attribute__((ext_vector_type(4)));

struct hl16 { _Float16 h, l; };
__device__ __forceinline__ hl16 split2(float v) {
    hl16 r;
    r.h = (_Float16)v;
    r.l = (_Float16)(v - (float)r.h);
    return r;
}

// Pre-split weight table offsets (in halves)
#define WT_SLOT 65536
#define FG1H_OFF 1048576
#define FG1L_OFF (FG1H_OFF + 16384)
#define CW2H_OFF (FG1H_OFF + 32768)
#define CW2L_OFF (FG1H_OFF + 49152)
#define CW3H_OFF (FG1H_OFF + 65536)
#define CW3L_OFF (CW3H_OFF + 131072)

// ---------------------------------------------------------------------------
// One-time: split all MFMA-path weights into fp16 hi/lo, [n][k] layout.
__global__ __launch_bounds__(256) void prep_split_k(
    const float* __restrict__ Wq, const float* __restrict__ Wk,
    const float* __restrict__ Wv, const float* __restrict__ Wo,
    const float* __restrict__ fgw1, const float* __restrict__ cw2,
    const float* __restrict__ cw3, _Float16* __restrict__ wt) {
    int e = blockIdx.x * 256 + threadIdx.x;
    if (e < 524288) {
        int slot = e >> 16;  // l*4 + mat
        int l = slot >> 2, mat = slot & 3;
        int r = e & 65535;
        int n = r >> 8, k = r & 255;
        const float* W = mat == 0 ? Wq : mat == 1 ? Wk : mat == 2 ? Wv : Wo;
        hl16 s = split2(W[(size_t)l * 65536 + k * 256 + n]);
        wt[(size_t)(2 * slot) * WT_SLOT + n * 256 + k] = s.h;
        wt[(size_t)(2 * slot + 1) * WT_SLOT + n * 256 + k] = s.l;
    } else if (e < 524288 + 16384) {
        int r = e - 524288;
        hl16 s = split2(fgw1[r]);
        wt[FG1H_OFF + r] = s.h;
        wt[FG1L_OFF + r] = s.l;
    } else if (e < 524288 + 32768) {
        int r = e - (524288 + 16384);
        hl16 s = split2(cw2[r]);
        wt[CW2H_OFF + r] = s.h;
        wt[CW2L_OFF + r] = s.l;
    } else if (e < 524288 + 32768 + 131072) {
        int r = e - (524288 + 32768);
        hl16 s = split2(cw3[r]);
        wt[CW3H_OFF + r] = s.h;
        wt[CW3L_OFF + r] = s.l;
    }
}

// ---------------------------------------------------------------------------
// Transpose (B,C,N)->(B,N,C) and emit fp32 + fp16 hi/lo.
__global__ __launch_bounds__(256) void transpose_split_k(const float* __restrict__ in,
                                                         float* __restrict__ out,
                                                         _Float16* __restrict__ oh,
                                                         _Float16* __restrict__ ol) {
    __shared__ float tls[32][33];
    int n0 = blockIdx.x * 32, c0 = blockIdx.y * 32, b = blockIdx.z;
    const float* ip = in + (size_t)b * CC * NN;
    size_t ob = (size_t)b * NN * CC;
    int tx = threadIdx.x, ty = threadIdx.y;
#pragma unroll
    for (int i = 0; i < 4; ++i)
        tls[ty + i * 8][tx] = ip[(size_t)(c0 + ty + i * 8) * NN + n0 + tx];
    __syncthreads();
#pragma unroll
    for (int i = 0; i < 4; ++i) {
        size_t oi = ob + (size_t)(n0 + ty + i * 8) * CC + c0 + tx;
        float v = tls[tx][ty + i * 8];
        out[oi] = v;
        hl16 s = split2(v);
        oh[oi] = s.h;
        ol[oi] = s.l;
    }
}

// ---------------------------------------------------------------------------
// Generic fp32 GEMM (small shapes: fg2, fg3, cw1)
template <bool TRANSB, bool BIAS>
__global__ __launch_bounds__(256) void gemm_k(const float* __restrict__ A,
                                              const float* __restrict__ Bm,
                                              const float* __restrict__ bias,
                                              float* __restrict__ Cm,
                                              int M, int Nc, int K) {
    __shared__ float As[16][68];
    __shared__ float Bs[16][68];
    int t = threadIdx.x;
    int tx = t & 15, ty = t >> 4;
    int row0 = blockIdx.y * 64, col0 = blockIdx.x * 64;
    float acc[4][4] = {};
    for (int k0 = 0; k0 < K; k0 += 16) {
#pragma unroll
        for (int p = 0; p < 4; ++p) {
            int i = t + 256 * p;
            int m = i >> 4, k = i & 15;
            int gm = row0 + m, gk = k0 + k;
            As[k][m] = (gm < M && gk < K) ? A[(size_t)gm * K + gk] : 0.f;
        }
#pragma unroll
        for (int p = 0; p < 4; ++p) {
            int i = t + 256 * p;
            if (TRANSB) {
                int k = i & 15, n = i >> 4;
                int gn = col0 + n, gk = k0 + k;
                Bs[k][n] = (gn < Nc && gk < K) ? Bm[(size_t)gn * K + gk] : 0.f;
            } else {
                int n = i & 63, k = i >> 6;
                int gn = col0 + n, gk = k0 + k;
                Bs[k][n] = (gn < Nc && gk < K) ? Bm[(size_t)gk * Nc + gn] : 0.f;
            }
        }
        __syncthreads();
#pragma unroll
        for (int kk = 0; kk < 16; ++kk) {
            float4 a4 = *(const float4*)&As[kk][ty * 4];
            float4 b4 = *(const float4*)&Bs[kk][tx * 4];
            float av[4] = {a4.x, a4.y, a4.z, a4.w};
            float bv[4] = {b4.x, b4.y, b4.z, b4.w};
#pragma unroll
            for (int i = 0; i < 4; ++i)
#pragma unroll
                for (int j = 0; j < 4; ++j) acc[i][j] = fmaf(av[i], bv[j], acc[i][j]);
        }
        __syncthreads();
    }
#pragma unroll
    for (int i = 0; i < 4; ++i) {
        int r = row0 + ty * 4 + i;
        if (r >= M) continue;
#pragma unroll
        for (int j = 0; j < 4; ++j) {
            int c = col0 + tx * 4 + j;
            if (c >= Nc) continue;
            float v = acc[i][j];
            if (BIAS) v += bias[c];
            Cm[(size_t)r * Nc + c] = v;
        }
    }
}

// ---------------------------------------------------------------------------
// Pre-split fp16 MFMA GEMM. A: Ah/Al [M][K] fp16; B: Bh/Bl [N][K] fp16.
// C = A*B via Ah*Bh + Ah*Bl + Al*Bh. Requires M%TM==0, Nc%64==0, K%32==0.
#define EPI_F32 0
#define EPI_QK 1
#define EPI_VT 2

template <int TM>
__device__ __forceinline__ void gemm_h_body(
    const _Float16* __restrict__ Ah, const _Float16* __restrict__ Al,
    const _Float16* __restrict__ Bh, const _Float16* __restrict__ Bl,
    const float* __restrict__ bias, float* __restrict__ Cf,
    _Float16* __restrict__ Ch, _Float16* __restrict__ Cl,
    int Nc, int K, int row0, int col0, int mode, float scl,
    _Float16* sAh, _Float16* sAl, _Float16* sBh, _Float16* sBl) {
    int t = threadIdx.x, w = t >> 6, lane = t & 63;
    int col = lane & 15, quad = lane >> 4;
    const int m0w = (TM == 128) ? (w & 1) * 64 : 0;
    const int n0w = (TM == 128) ? (w >> 1) * 32 : w * 16;
    constexpr int NT = (TM == 128) ? 2 : 1;
    constexpr int AC = TM / 64;  // A chunks per plane per thread
    f32x4 acc[4][NT];
#pragma unroll
    for (int i = 0; i < 4; ++i)
#pragma unroll
        for (int j = 0; j < NT; ++j) acc[i][j] = (f32x4){0.f, 0.f, 0.f, 0.f};

    for (int k0 = 0; k0 < K; k0 += 32) {
        f16x8 rah[AC], ral[AC], rbh, rbl;
#pragma unroll
        for (int i = 0; i < AC; ++i) {
            int idx = t + 256 * i;
            int r = idx >> 2, off = (idx & 3) * 8;
            rah[i] = *(const f16x8*)(Ah + (size_t)(row0 + r) * K + k0 + off);
            ral[i] = *(const f16x8*)(Al + (size_t)(row0 + r) * K + k0 + off);
        }
        {
            int r = t >> 2, off = (t & 3) * 8;
            rbh = *(const f16x8*)(Bh + (size_t)(col0 + r) * K + k0 + off);
            rbl = *(const f16x8*)(Bl + (size_t)(col0 + r) * K + k0 + off);
        }
        __syncthreads();
#pragma unroll
        for (int i = 0; i < AC; ++i) {
            int idx = t + 256 * i;
            int r = idx >> 2, off = (idx & 3) * 8;
            *(f16x8*)&sAh[r * 40 + off] = rah[i];
            *(f16x8*)&sAl[r * 40 + off] = ral[i];
        }
        {
            int r = t >> 2, off = (t & 3) * 8;
            *(f16x8*)&sBh[r * 40 + off] = rbh;
            *(f16x8*)&sBl[r * 40 + off] = rbl;
        }
        __syncthreads();
        f16x8 fah[4], fal[4], fbh[NT], fbl[NT];
#pragma unroll
        for (int i = 0; i < 4; ++i) {
            fah[i] = *(const f16x8*)&sAh[(m0w + i * 16 + col) * 40 + quad * 8];
            fal[i] = *(const f16x8*)&sAl[(m0w + i * 16 + col) * 40 + quad * 8];
        }
#pragma unroll
        for (int j = 0; j < NT; ++j) {
            fbh[j] = *(const f16x8*)&sBh[(n0w + j * 16 + col) * 40 + quad * 8];
            fbl[j] = *(const f16x8*)&sBl[(n0w + j * 16 + col) * 40 + quad * 8];
        }
#pragma unroll
        for (int i = 0; i < 4; ++i)
#pragma unroll
            for (int j = 0; j < NT; ++j) {
                acc[i][j] = __builtin_amdgcn_mfma_f32_16x16x32_f16(fah[i], fbh[j], acc[i][j], 0, 0, 0);
                acc[i][j] = __builtin_amdgcn_mfma_f32_16x16x32_f16(fah[i], fbl[j], acc[i][j], 0, 0, 0);
                acc[i][j] = __builtin_amdgcn_mfma_f32_16x16x32_f16(fal[i], fbh[j], acc[i][j], 0, 0, 0);
            }
    }
    // epilogue: C col=lane&15 -> n, row=quad*4+r -> m
#pragma unroll
    for (int i = 0; i < 4; ++i)
#pragma unroll
        for (int j = 0; j < NT; ++j) {
            int n = col0 + n0w + j * 16 + col;
            int mb = row0 + m0w + i * 16 + quad * 4;
            if (mode == EPI_F32) {
                float bv = bias ? bias[n] : 0.f;
#pragma unroll
                for (int r = 0; r < 4; ++r)
                    Cf[(size_t)(mb + r) * Nc + n] = acc[i][j][r] + bv;
            } else if (mode == EPI_QK) {
#pragma unroll
                for (int r = 0; r < 4; ++r) {
                    hl16 s = split2(acc[i][j][r] * scl);
                    Ch[(size_t)(mb + r) * Nc + n] = s.h;
                    Cl[(size_t)(mb + r) * Nc + n] = s.l;
                }
            } else {  // EPI_VT: [b][h][d][token]
                int b = mb >> 11, token = mb & 2047;
                int h = n >> 5, d = n & 31;
                f16x4 h4, l4;
#pragma unroll
                for (int r = 0; r < 4; ++r) {
                    hl16 s = split2(acc[i][j][r]);
                    h4[r] = s.h;
                    l4[r] = s.l;
                }
                size_t dst = ((size_t)(b * HH + h) * DH + d) * NN + token;
                *(f16x4*)&Ch[dst] = h4;
                *(f16x4*)&Cl[dst] = l4;
            }
        }
}

template <int TM>
__global__ __launch_bounds__(256) void gemm_h_k(const _Float16* __restrict__ Ah,
                                                const _Float16* __restrict__ Al,
                                                const _Float16* __restrict__ Bh,
                                                const _Float16* __restrict__ Bl,
                                                const float* __restrict__ bias,
                                                float* __restrict__ Cf, int Nc, int K) {
    __shared__ _Float16 sAh[TM * 40], sAl[TM * 40], sBh[64 * 40], sBl[64 * 40];
    gemm_h_body<TM>(Ah, Al, Bh, Bl, bias, Cf, nullptr, nullptr, Nc, K,
                    blockIdx.y * TM, blockIdx.x * 64, EPI_F32, 1.f, sAh, sAl, sBh, sBl);
}

// Fused QKV: blockIdx.x in [0,12): mat = x>>2, col block = x&3.
__global__ __launch_bounds__(256) void qkv_h_k(const _Float16* __restrict__ Xh,
                                               const _Float16* __restrict__ Xl,
                                               const _Float16* __restrict__ wt, int layer,
                                               _Float16* Qh, _Float16* Ql,
                                               _Float16* Kh, _Float16* Kl,
                                               _Float16* Vh, _Float16* Vl) {
    __shared__ _Float16 sAh[128 * 40], sAl[128 * 40], sBh[64 * 40], sBl[64 * 40];
    int mat = blockIdx.x >> 2;
    int slot = (layer * 4 + mat) * 2;
    const _Float16* Bh = wt + (size_t)slot * WT_SLOT;
    const _Float16* Bl = wt + (size_t)(slot + 1) * WT_SLOT;
    _Float16* Ch = mat == 0 ? Qh : mat == 1 ? Kh : Vh;
    _Float16* Cl = mat == 0 ? Ql : mat == 1 ? Kl : Vl;
    int mode = (mat == 2) ? EPI_VT : EPI_QK;
    float scl = (mat == 0) ? 0.17677669529663687f : 1.f;
    gemm_h_body<128>(Xh, Xl, Bh, Bl, nullptr, nullptr, Ch, Cl, CC, CC,
                     blockIdx.y * 128, (blockIdx.x & 3) * 64, mode, scl, sAh, sAl, sBh, sBl);
}

// ---------------------------------------------------------------------------
// Attention v3: pre-split fp16 inputs; 64 q/block (16/wave), pure-copy staging.
// Scale already folded into Q. O written (split) back into Q buffer (same tokens).
__global__ __launch_bounds__(256) void attn3_k(_Float16* QOh, _Float16* QOl,
                                               const _Float16* __restrict__ Kh,
                                               const _Float16* __restrict__ Kl,
                                               const _Float16* __restrict__ Vh,
                                               const _Float16* __restrict__ Vl) {
    __shared__ _Float16 sKh[32 * 40], sKl[32 * 40], sVh[32 * 40], sVl[32 * 40];
    __shared__ _Float16 sPh[4][16 * 40], sPl[4][16 * 40];
    int t = threadIdx.x, w = t >> 6, lane = t & 63;
    int col = lane & 15, quad = lane >> 4;
    int bh = blockIdx.y, b = bh >> 3, h = bh & 7;
    int qbase = blockIdx.x * 64 + w * 16;

    // Q fragment (B-operand: [q=col][d=quad*8+j])
    size_t qoff = ((size_t)(b * NN + qbase + col)) * CC + h * DH + quad * 8;
    f16x8 qh = *(const f16x8*)(QOh + qoff);
    f16x8 ql = *(const f16x8*)(QOl + qoff);

    f32x4 o0 = {0.f, 0.f, 0.f, 0.f}, o1 = {0.f, 0.f, 0.f, 0.f};
    float mrun = -1e30f, lsum = 0.f;

    // staging: 512 x 16B chunks, 2 per thread. K planes: [key][d]; V planes: [d][key].
    int idx = t & 127, srow = idx >> 2, soff = (idx & 3) * 8;
    const _Float16* kg = (t < 128 ? Kh : Kl) + (size_t)b * NN * CC + h * DH;
    const _Float16* vg = (t < 128 ? Vh : Vl) + ((size_t)(b * HH + h) * DH) * NN;
    _Float16* dK = (t < 128 ? sKh : sKl) + srow * 40 + soff;
    _Float16* dV = (t < 128 ? sVh : sVl) + srow * 40 + soff;

    for (int k0 = 0; k0 < NN; k0 += 32) {
        f16x8 rk = *(const f16x8*)(kg + (size_t)(k0 + srow) * CC + soff);
        f16x8 rv = *(const f16x8*)(vg + (size_t)srow * NN + k0 + soff);
        __syncthreads();  // previous tile fully consumed
        *(f16x8*)dK = rk;
        *(f16x8*)dV = rv;
        __syncthreads();

        // QK^T (S^T = K·Q^T), two key subtiles
        f32x4 s0 = {0.f, 0.f, 0.f, 0.f}, s1 = {0.f, 0.f, 0.f, 0.f};
        {
            f16x8 ka = *(const f16x8*)&sKh[col * 40 + quad * 8];
            f16x8 kb = *(const f16x8*)&sKl[col * 40 + quad * 8];
            s0 = __builtin_amdgcn_mfma_f32_16x16x32_f16(ka, qh, s0, 0, 0, 0);
            s0 = __builtin_amdgcn_mfma_f32_16x16x32_f16(ka, ql, s0, 0, 0, 0);
            s0 = __builtin_amdgcn_mfma_f32_16x16x32_f16(kb, qh, s0, 0, 0, 0);
            f16x8 kc = *(const f16x8*)&sKh[(16 + col) * 40 + quad * 8];
            f16x8 kd = *(const f16x8*)&sKl[(16 + col) * 40 + quad * 8];
            s1 = __builtin_amdgcn_mfma_f32_16x16x32_f16(kc, qh, s1, 0, 0, 0);
            s1 = __builtin_amdgcn_mfma_f32_16x16x32_f16(kc, ql, s1, 0, 0, 0);
            s1 = __builtin_amdgcn_mfma_f32_16x16x32_f16(kd, qh, s1, 0, 0, 0);
        }

        // online softmax (per query col; 32 keys spread over quads via shfl)
        float sv[8] = {s0[0], s0[1], s0[2], s0[3], s1[0], s1[1], s1[2], s1[3]};
        float tm = sv[0];
#pragma unroll
        for (int j = 1; j < 8; ++j) tm = fmaxf(tm, sv[j]);
        tm = fmaxf(tm, __shfl_xor(tm, 16));
        tm = fmaxf(tm, __shfl_xor(tm, 32));
        float nm = fmaxf(mrun, tm);
        float alpha = __expf(mrun - nm);
        float p[8], rs = 0.f;
#pragma unroll
        for (int j = 0; j < 8; ++j) {
            p[j] = __expf(sv[j] - nm);
            rs += p[j];
        }
        rs += __shfl_xor(rs, 16);
        rs += __shfl_xor(rs, 32);
        lsum = lsum * alpha + rs;
        mrun = nm;
        o0.x *= alpha; o0.y *= alpha; o0.z *= alpha; o0.w *= alpha;
        o1.x *= alpha; o1.y *= alpha; o1.z *= alpha; o1.w *= alpha;

        // P split + per-wave LDS transpose
        f16x4 ph0, pl0, ph1, pl1;
#pragma unroll
        for (int j = 0; j < 4; ++j) {
            hl16 a = split2(p[j]);
            ph0[j] = a.h; pl0[j] = a.l;
            hl16 c = split2(p[4 + j]);
            ph1[j] = c.h; pl1[j] = c.l;
        }
        *(f16x4*)&sPh[w][col * 40 + quad * 4] = ph0;
        *(f16x4*)&sPh[w][col * 40 + 16 + quad * 4] = ph1;
        *(f16x4*)&sPl[w][col * 40 + quad * 4] = pl0;
        *(f16x4*)&sPl[w][col * 40 + 16 + quad * 4] = pl1;
        __asm__ volatile("s_waitcnt lgkmcnt(0)" ::: "memory");
        f16x8 pH = *(const f16x8*)&sPh[w][col * 40 + quad * 8];
        f16x8 pL = *(const f16x8*)&sPl[w][col * 40 + quad * 8];

        // PV: O^T += V^T · P^T, two d-halves
        {
            f16x8 va = *(const f16x8*)&sVh[col * 40 + quad * 8];
            f16x8 vb = *(const f16x8*)&sVl[col * 40 + quad * 8];
            o0 = __builtin_amdgcn_mfma_f32_16x16x32_f16(va, pH, o0, 0, 0, 0);
            o0 = __builtin_amdgcn_mfma_f32_16x16x32_f16(va, pL, o0, 0, 0, 0);
            o0 = __builtin_amdgcn_mfma_f32_16x16x32_f16(vb, pH, o0, 0, 0, 0);
            f16x8 vc = *(const f16x8*)&sVh[(16 + col) * 40 + quad * 8];
            f16x8 vd = *(const f16x8*)&sVl[(16 + col) * 40 + quad * 8];
            o1 = __builtin_amdgcn_mfma_f32_16x16x32_f16(vc, pH, o1, 0, 0, 0);
            o1 = __builtin_amdgcn_mfma_f32_16x16x32_f16(vc, pL, o1, 0, 0, 0);
            o1 = __builtin_amdgcn_mfma_f32_16x16x32_f16(vd, pH, o1, 0, 0, 0);
        }
    }

    // epilogue: O^T layout col=q, row=d. Write split O into Q buffer (own tokens).
    float inv = 1.f / lsum;
    f32x4 oo[2] = {o0, o1};
#pragma unroll
    for (int dh = 0; dh < 2; ++dh) {
        f16x4 h4, l4;
#pragma unroll
        for (int r = 0; r < 4; ++r) {
            hl16 s = split2(oo[dh][r] * inv);
            h4[r] = s.h;
            l4[r] = s.l;
        }
        size_t dsti = ((size_t)(b * NN + qbase + col)) * CC + h * DH + dh * 16 + quad * 4;
        *(f16x4*)&QOh[dsti] = h4;
        *(f16x4*)&QOl[dsti] = l4;
    }
}

// ---------------------------------------------------------------------------
// X = LayerNorm(X + P); also emit fp16 hi/lo of result.
__global__ __launch_bounds__(256) void add_ln_k(float* __restrict__ X,
                                                const float* __restrict__ P,
                                                const float* __restrict__ g,
                                                const float* __restrict__ bta,
                                                _Float16* __restrict__ Xh,
                                                _Float16* __restrict__ Xl) {
    int wave = threadIdx.x >> 6, lane = threadIdx.x & 63;
    size_t row = (size_t)blockIdx.x * 4 + wave;
    size_t base = row * CC + lane * 4;
    float4 x = *(float4*)(X + base);
    float4 p = *(const float4*)(P + base);
    x.x += p.x; x.y += p.y; x.z += p.z; x.w += p.w;
    float sum = x.x + x.y + x.z + x.w;
    float ss = x.x * x.x + x.y * x.y + x.z * x.z + x.w * x.w;
#pragma unroll
    for (int off = 32; off; off >>= 1) {
        sum += __shfl_down(sum, off);
        ss += __shfl_down(ss, off);
    }
    sum = __shfl(sum, 0);
    ss = __shfl(ss, 0);
    float mean = sum * (1.f / 256.f);
    float var = ss * (1.f / 256.f) - mean * mean;
    float wn = rsqrtf(var + EPSV);
    float4 gg = *(const float4*)(g + lane * 4);
    float4 bb = *(const float4*)(bta + lane * 4);
    x.x = (x.x - mean) * wn * gg.x + bb.x;
    x.y = (x.y - mean) * wn * gg.y + bb.y;
    x.z = (x.z - mean) * wn * gg.z + bb.z;
    x.w = (x.w - mean) * wn * gg.w + bb.w;
    *(float4*)(X + base) = x;
    f16x4 h4, l4;
    float xv[4] = {x.x, x.y, x.z, x.w};
#pragma unroll
    for (int j = 0; j < 4; ++j) {
        hl16 s = split2(xv[j]);
        h4[j] = s.h;
        l4[j] = s.l;
    }
    *(f16x4*)&Xh[base] = h4;
    *(f16x4*)&Xl[base] = l4;
}

// ---------------------------------------------------------------------------
__global__ __launch_bounds__(256) void bn_stats_k(const float* __restrict__ Hm,
                                                  float* __restrict__ stats,
                                                  int M, int Cc) {
    int c = blockIdx.x;
    int t = threadIdx.x;
    float s = 0.f, ss = 0.f;
    for (int r = t; r < M; r += 256) {
        float v = Hm[(size_t)r * Cc + c];
        s += v;
        ss += v * v;
    }
    __shared__ float sh0[256], sh1[256];
    sh0[t] = s; sh1[t] = ss;
    __syncthreads();
    for (int st = 128; st; st >>= 1) {
        if (t < st) { sh0[t] += sh0[t + st]; sh1[t] += sh1[t + st]; }
        __syncthreads();
    }
    if (t == 0) {
        float mean = sh0[0] / (float)M;
        stats[c] = mean;
        stats[Cc + c] = sh1[0] / (float)M - mean * mean;
    }
}

__global__ __launch_bounds__(256) void bn_apply_k(const float* __restrict__ in,
                                                  float* __restrict__ out,
                                                  const float* __restrict__ stats,
                                                  const float* __restrict__ gam,
                                                  const float* __restrict__ bet,
                                                  int total, int Cc, float alpha) {
    int i = blockIdx.x * 256 + threadIdx.x;
    if (i >= total) return;
    int c = i % Cc;
    float v = (in[i] - stats[c]) * rsqrtf(stats[Cc + c] + EPSV) * gam[c] + bet[c];
    out[i] = v > 0.f ? v : alpha * v;
}

__global__ __launch_bounds__(256) void bn_apply_split_k(const float* __restrict__ in,
                                                        _Float16* __restrict__ oh,
                                                        _Float16* __restrict__ ol,
                                                        const float* __restrict__ stats,
                                                        const float* __restrict__ gam,
                                                        const float* __restrict__ bet,
                                                        int total, int Cc, float alpha) {
    int i = blockIdx.x * 256 + threadIdx.x;
    if (i >= total) return;
    int c = i % Cc;
    float v = (in[i] - stats[c]) * rsqrtf(stats[Cc + c] + EPSV) * gam[c] + bet[c];
    v = v > 0.f ? v : alpha * v;
    hl16 s = split2(v);
    oh[i] = s.h;
    ol[i] = s.l;
}

// ---------------------------------------------------------------------------
// Fused: per (b, channel) argmax -> ball query -> gather grouped coords.
__global__ __launch_bounds__(64) void select_k(const float* __restrict__ H3,
                                               const float* __restrict__ pts,
                                               float* __restrict__ G0) {
    int bs = blockIdx.x;
    int b = bs >> 4, ch = bs & 15;
    int lane = threadIdx.x;
    // argmax over N (tie -> lowest index)
    float best = -1e30f;
    int bn = 0;
    for (int n = lane; n < NN; n += 64) {
        float v = H3[((size_t)(b * NN + n)) * 16 + ch];
        if (v > best) { best = v; bn = n; }
    }
#pragma unroll
    for (int off = 32; off; off >>= 1) {
        float ov = __shfl_xor(best, off);
        int on = __shfl_xor(bn, off);
        if (ov > best || (ov == best && on < bn)) { best = ov; bn = on; }
    }
    const float* px = pts + (size_t)b * 3 * NN;
    float qx = px[bn], qy = px[NN + bn], qz = px[2 * NN + bn];
    float qq = (qx * qx + qy * qy) + qz * qz;
    // ball query: first NSAMPLE in-order with sqd <= R^2
    __shared__ int sgi[NSAMPLE];
    const float R2 = 0.09f;
    int cnt = 0;
    for (int base = 0; base < NN && cnt < NSAMPLE; base += 64) {
        int n = base + lane;
        float x = px[n], y = px[NN + n], z = px[2 * NN + n];
        float pp = (x * x + y * y) + z * z;
        float dot = (qx * x + qy * y) + qz * z;
        float sqd = (qq + pp) - 2.f * dot;
        bool ok = !(sqd > R2);
        unsigned long long mk = __ballot(ok);
        int pos = cnt + (int)__popcll(mk & ((1ull << lane) - 1ull));
        if (ok && pos < NSAMPLE) sgi[pos] = n;
        cnt += (int)__popcll(mk);
    }
    __syncthreads();
    int g0 = sgi[0];
    if (lane >= cnt && lane < NSAMPLE) sgi[lane] = g0;
    __syncthreads();
    // gather rows (bs, k) x 3
    for (int e = lane; e < KK * 3; e += 64) {
        int k = e / 3, d = e % 3;
        int src = (k == 0) ? bn : sgi[k - 1];
        G0[((size_t)bs * KK + k) * 3 + d] = px[d * NN + src];
    }
}

// ---------------------------------------------------------------------------
__global__ __launch_bounds__(256) void maxpool_k(const float* __restrict__ G3,
                                                 float* __restrict__ out) {
    int i = blockIdx.x * 256 + threadIdx.x;
    if (i >= BB * 512 * SS) return;
    int o = i & 511;
    int s = (i >> 9) & 15;
    int b = i >> 13;
    const float* p = G3 + ((size_t)(b * SS + s) * KK) * 512 + o;
    float mx = p[0];
#pragma unroll
    for (int k = 1; k < KK; ++k) mx = fmaxf(mx, p[(size_t)k * 512]);
    out[((size_t)(b * 512 + o)) * SS + s] = mx;
}

// ---------------------------------------------------------------------------
extern "C" void kernel_launch(void* const* d_in, const int* in_sizes, int n_in,
                              void* d_out, int out_size, void* d_ws, size_t ws_size,
                              hipStream_t stream) {
    const float* hoch = (const float*)d_in[0];
    const float* pts = (const float*)d_in[1];
    const float* Wq = (const float*)d_in[2];
    const float* Wk = (const float*)d_in[3];
    const float* Wv = (const float*)d_in[4];
    const float* Wo = (const float*)d_in[5];
    const float* ln_g = (const float*)d_in[6];
    const float* ln_b = (const float*)d_in[7];
    const float* fg_w1 = (const float*)d_in[8];
    const float* fg_b1 = (const float*)d_in[9];
    const float* fg_w2 = (const float*)d_in[10];
    const float* fg_b2 = (const float*)d_in[11];
    const float* fg_w3 = (const float*)d_in[12];
    const float* fg_b3 = (const float*)d_in[13];
    const float* fg_g1 = (const float*)d_in[14];
    const float* fg_be1 = (const float*)d_in[15];
    const float* fg_g2 = (const float*)d_in[16];
    const float* fg_be2 = (const float*)d_in[17];
    const float* fg_g3 = (const float*)d_in[18];
    const float* fg_be3 = (const float*)d_in[19];
    const float* cw1 = (const float*)d_in[20];
    const float* cw2 = (const float*)d_in[21];
    const float* cw3 = (const float*)d_in[22];
    const float* cg1 = (const float*)d_in[23];
    const float* cb1 = (const float*)d_in[24];
    const float* cg2 = (const float*)d_in[25];
    const float* cb2 = (const float*)d_in[26];
    const float* cg3 = (const float*)d_in[27];
    const float* cb3 = (const float*)d_in[28];
    float* out = (float*)d_out;

    float* ws = (float*)d_ws;
    const size_t M1 = (size_t)BB * NN * CC;  // 2,097,152
    float* X = ws;
    float* bA = ws + M1;
    float* bB = ws + 2 * M1;
    float* bC = ws + 3 * M1;
    _Float16* hb = (_Float16*)(ws + 4 * M1);
    _Float16* Xh = hb;
    _Float16* Xl = hb + M1;
    _Float16* Qh = hb + 2 * M1;  // also O (attn writes split O back here)
    _Float16* Ql = hb + 3 * M1;
    _Float16* Kh = hb + 4 * M1;  // also conv activations post-transformer
    _Float16* Kl = hb + 5 * M1;
    _Float16* Vh = hb + 6 * M1;
    _Float16* Vl = hb + 7 * M1;
    _Float16* wt = hb + 8 * M1;  // 1,376,256 halves
    float* sm = ws + 4 * M1 + (9 * M1) / 2;  // past halves region
    float* stats = sm;        // 1024
    float* G0 = sm + 1024;    // 6336

    prep_split_k<<<2688, 256, 0, stream>>>(Wq, Wk, Wv, Wo, fg_w1, cw2, cw3, wt);
    transpose_split_k<<<dim3(NN / 32, CC / 32, BB), dim3(32, 8), 0, stream>>>(hoch, X, Xh, Xl);

    const int Mrows = BB * NN;  // 8192
    for (int l = 0; l < LL; ++l) {
        qkv_h_k<<<dim3(12, Mrows / 128), 256, 0, stream>>>(Xh, Xl, wt, l, Qh, Ql, Kh, Kl, Vh, Vl);
        attn3_k<<<dim3(NN / 64, BB * HH), 256, 0, stream>>>(Qh, Ql, Kh, Kl, Vh, Vl);
        int slot = (l * 4 + 3) * 2;
        gemm_h_k<128><<<dim3(CC / 64, Mrows / 128), 256, 0, stream>>>(
            Qh, Ql, wt + (size_t)slot * WT_SLOT, wt + (size_t)(slot + 1) * WT_SLOT,
            nullptr, bA, CC, CC);
        add_ln_k<<<Mrows / 4, 256, 0, stream>>>(X, bA, ln_g + l * CC, ln_b + l * CC, Xh, Xl);
    }

    // fg head: 256 -> 64 -> 32 -> 16, BN+ReLU each
    gemm_h_k<64><<<dim3(1, Mrows / 64), 256, 0, stream>>>(Xh, Xl, wt + FG1H_OFF, wt + FG1L_OFF, fg_b1, bA, 64, 256);
    bn_stats_k<<<64, 256, 0, stream>>>(bA, stats, Mrows, 64);
    bn_apply_k<<<(Mrows * 64 + 255) / 256, 256, 0, stream>>>(bA, bA, stats, fg_g1, fg_be1, Mrows * 64, 64, 0.f);
    gemm_k<true, true><<<dim3(1, Mrows / 64), 256, 0, stream>>>(bA, fg_w2, fg_b2, bB, Mrows, 32, 64);
    bn_stats_k<<<32, 256, 0, stream>>>(bB, stats, Mrows, 32);
    bn_apply_k<<<(Mrows * 32 + 255) / 256, 256, 0, stream>>>(bB, bB, stats, fg_g2, fg_be2, Mrows * 32, 32, 0.f);
    gemm_k<true, true><<<dim3(1, Mrows / 64), 256, 0, stream>>>(bB, fg_w3, fg_b3, bC, Mrows, 16, 32);
    bn_stats_k<<<16, 256, 0, stream>>>(bC, stats, Mrows, 16);
    bn_apply_k<<<(Mrows * 16 + 255) / 256, 256, 0, stream>>>(bC, bC, stats, fg_g3, fg_be3, Mrows * 16, 16, 0.f);

    // selection + grouping (fused)
    select_k<<<BB * SS, 64, 0, stream>>>(bC, pts, G0);

    // conv stack: 3 -> 64 -> 256 -> 512, BN+LeakyReLU(0.2)
    const int Mg = BB * SS * KK;  // 2112 = 33*64
    gemm_k<true, false><<<dim3(1, Mg / 64), 256, 0, stream>>>(G0, cw1, nullptr, bA, Mg, 64, 3);
    bn_stats_k<<<64, 256, 0, stream>>>(bA, stats, Mg, 64);
    bn_apply_split_k<<<(Mg * 64 + 255) / 256, 256, 0, stream>>>(bA, Kh, Kl, stats, cg1, cb1, Mg * 64, 64, 0.2f);
    gemm_h_k<64><<<dim3(4, Mg / 64), 256, 0, stream>>>(Kh, Kl, wt + CW2H_OFF, wt + CW2L_OFF, nullptr, bB, 256, 64);
    bn_stats_k<<<256, 256, 0, stream>>>(bB, stats, Mg, 256);
    bn_apply_split_k<<<(Mg * 256 + 255) / 256, 256, 0, stream>>>(bB, Kh, Kl, stats, cg2, cb2, Mg * 256, 256, 0.2f);
    gemm_h_k<64><<<dim3(8, Mg / 64), 256, 0, stream>>>(Kh, Kl, wt + CW3H_OFF, wt + CW3L_OFF, nullptr, bC, 512, 256);
    bn_stats_k<<<512, 256, 0, stream>>>(bC, stats, Mg, 512);
    bn_apply_k<<<(Mg * 512 + 255) / 256, 256, 0, stream>>>(bC, bC, stats, cg3, cb3, Mg * 512, 512, 0.2f);

    maxpool_k<<<(BB * 512 * SS + 255) / 256, 256, 0, stream>>>(bC, out);

    (void)in_sizes; (void)n_in; (void)out_size; (void)ws_size;
}

// Round 6
// 536.363 us; speedup vs baseline: 4.6241x; 1.0106x over previous
//
#include <hip/hip_runtime.h>
#include <hip/hip_bf16.h>
#include <math.h>

// Problem constants
#define BB 4
#define NN 2048
#define CC 256
#define HH 8
#define DH 32
#define LL 2
#define SS 16
#define KK 33
#define NSAMPLE 32
#define EPSV 1e-5f

typedef _Float16 f16x8 __attribute__((ext_vector_type(8)));
typedef _Float16 f16x4 __attribute__((ext_vector_type(4)));
typedef float f32x4 __attribute__((ext_vector_type(4)));

struct hl16 { _Float16 h, l; };
__device__ __forceinline__ hl16 split2(float v) {
    hl16 r;
    r.h = (_Float16)v;
    r.l = (_Float16)(v - (float)r.h);
    return r;
}

// Pre-split weight table offsets (in halves)
#define WT_SLOT 65536
#define FG1H_OFF 1048576
#define FG1L_OFF (FG1H_OFF + 16384)
#define CW2H_OFF (FG1H_OFF + 32768)
#define CW2L_OFF (FG1H_OFF + 49152)
#define CW3H_OFF (FG1H_OFF + 65536)
#define CW3L_OFF (CW3H_OFF + 131072)

// ---------------------------------------------------------------------------
__global__ __launch_bounds__(256) void prep_split_k(
    const float* __restrict__ Wq, const float* __restrict__ Wk,
    const float* __restrict__ Wv, const float* __restrict__ Wo,
    const float* __restrict__ fgw1, const float* __restrict__ cw2,
    const float* __restrict__ cw3, _Float16* __restrict__ wt) {
    int e = blockIdx.x * 256 + threadIdx.x;
    if (e < 524288) {
        int slot = e >> 16;  // l*4 + mat
        int l = slot >> 2, mat = slot & 3;
        int r = e & 65535;
        int n = r >> 8, k = r & 255;
        const float* W = mat == 0 ? Wq : mat == 1 ? Wk : mat == 2 ? Wv : Wo;
        hl16 s = split2(W[(size_t)l * 65536 + k * 256 + n]);
        wt[(size_t)(2 * slot) * WT_SLOT + n * 256 + k] = s.h;
        wt[(size_t)(2 * slot + 1) * WT_SLOT + n * 256 + k] = s.l;
    } else if (e < 524288 + 16384) {
        int r = e - 524288;
        hl16 s = split2(fgw1[r]);
        wt[FG1H_OFF + r] = s.h;
        wt[FG1L_OFF + r] = s.l;
    } else if (e < 524288 + 32768) {
        int r = e - (524288 + 16384);
        hl16 s = split2(cw2[r]);
        wt[CW2H_OFF + r] = s.h;
        wt[CW2L_OFF + r] = s.l;
    } else if (e < 524288 + 32768 + 131072) {
        int r = e - (524288 + 32768);
        hl16 s = split2(cw3[r]);
        wt[CW3H_OFF + r] = s.h;
        wt[CW3L_OFF + r] = s.l;
    }
}

// ---------------------------------------------------------------------------
__global__ __launch_bounds__(256) void transpose_split_k(const float* __restrict__ in,
                                                         float* __restrict__ out,
                                                         _Float16* __restrict__ oh,
                                                         _Float16* __restrict__ ol) {
    __shared__ float tls[32][33];
    int n0 = blockIdx.x * 32, c0 = blockIdx.y * 32, b = blockIdx.z;
    const float* ip = in + (size_t)b * CC * NN;
    size_t ob = (size_t)b * NN * CC;
    int tx = threadIdx.x, ty = threadIdx.y;
#pragma unroll
    for (int i = 0; i < 4; ++i)
        tls[ty + i * 8][tx] = ip[(size_t)(c0 + ty + i * 8) * NN + n0 + tx];
    __syncthreads();
#pragma unroll
    for (int i = 0; i < 4; ++i) {
        size_t oi = ob + (size_t)(n0 + ty + i * 8) * CC + c0 + tx;
        float v = tls[tx][ty + i * 8];
        out[oi] = v;
        hl16 s = split2(v);
        oh[oi] = s.h;
        ol[oi] = s.l;
    }
}

// ---------------------------------------------------------------------------
// Generic fp32 GEMM (small shapes: fg2, fg3, cw1)
template <bool TRANSB, bool BIAS>
__global__ __launch_bounds__(256) void gemm_k(const float* __restrict__ A,
                                              const float* __restrict__ Bm,
                                              const float* __restrict__ bias,
                                              float* __restrict__ Cm,
                                              int M, int Nc, int K) {
    __shared__ float As[16][68];
    __shared__ float Bs[16][68];
    int t = threadIdx.x;
    int tx = t & 15, ty = t >> 4;
    int row0 = blockIdx.y * 64, col0 = blockIdx.x * 64;
    float acc[4][4] = {};
    for (int k0 = 0; k0 < K; k0 += 16) {
#pragma unroll
        for (int p = 0; p < 4; ++p) {
            int i = t + 256 * p;
            int m = i >> 4, k = i & 15;
            int gm = row0 + m, gk = k0 + k;
            As[k][m] = (gm < M && gk < K) ? A[(size_t)gm * K + gk] : 0.f;
        }
#pragma unroll
        for (int p = 0; p < 4; ++p) {
            int i = t + 256 * p;
            if (TRANSB) {
                int k = i & 15, n = i >> 4;
                int gn = col0 + n, gk = k0 + k;
                Bs[k][n] = (gn < Nc && gk < K) ? Bm[(size_t)gn * K + gk] : 0.f;
            } else {
                int n = i & 63, k = i >> 6;
                int gn = col0 + n, gk = k0 + k;
                Bs[k][n] = (gn < Nc && gk < K) ? Bm[(size_t)gk * Nc + gn] : 0.f;
            }
        }
        __syncthreads();
#pragma unroll
        for (int kk = 0; kk < 16; ++kk) {
            float4 a4 = *(const float4*)&As[kk][ty * 4];
            float4 b4 = *(const float4*)&Bs[kk][tx * 4];
            float av[4] = {a4.x, a4.y, a4.z, a4.w};
            float bv[4] = {b4.x, b4.y, b4.z, b4.w};
#pragma unroll
            for (int i = 0; i < 4; ++i)
#pragma unroll
                for (int j = 0; j < 4; ++j) acc[i][j] = fmaf(av[i], bv[j], acc[i][j]);
        }
        __syncthreads();
    }
#pragma unroll
    for (int i = 0; i < 4; ++i) {
        int r = row0 + ty * 4 + i;
        if (r >= M) continue;
#pragma unroll
        for (int j = 0; j < 4; ++j) {
            int c = col0 + tx * 4 + j;
            if (c >= Nc) continue;
            float v = acc[i][j];
            if (BIAS) v += bias[c];
            Cm[(size_t)r * Nc + c] = v;
        }
    }
}

// ---------------------------------------------------------------------------
// Pre-split fp16 MFMA GEMM. A: Ah/Al [M][K] fp16; B: Bh/Bl [N][K] fp16.
#define EPI_F32 0
#define EPI_QK 1
#define EPI_VT 2

template <int TM>
__device__ __forceinline__ void gemm_h_body(
    const _Float16* __restrict__ Ah, const _Float16* __restrict__ Al,
    const _Float16* __restrict__ Bh, const _Float16* __restrict__ Bl,
    const float* __restrict__ bias, float* __restrict__ Cf,
    _Float16* __restrict__ Ch, _Float16* __restrict__ Cl,
    int Nc, int K, int row0, int col0, int mode, float scl,
    _Float16* sAh, _Float16* sAl, _Float16* sBh, _Float16* sBl) {
    int t = threadIdx.x, w = t >> 6, lane = t & 63;
    int col = lane & 15, quad = lane >> 4;
    const int m0w = (TM == 128) ? (w & 1) * 64 : 0;
    const int n0w = (TM == 128) ? (w >> 1) * 32 : w * 16;
    constexpr int NT = (TM == 128) ? 2 : 1;
    constexpr int AC = TM / 64;
    f32x4 acc[4][NT];
#pragma unroll
    for (int i = 0; i < 4; ++i)
#pragma unroll
        for (int j = 0; j < NT; ++j) acc[i][j] = (f32x4){0.f, 0.f, 0.f, 0.f};

    for (int k0 = 0; k0 < K; k0 += 32) {
        f16x8 rah[AC], ral[AC], rbh, rbl;
#pragma unroll
        for (int i = 0; i < AC; ++i) {
            int idx = t + 256 * i;
            int r = idx >> 2, off = (idx & 3) * 8;
            rah[i] = *(const f16x8*)(Ah + (size_t)(row0 + r) * K + k0 + off);
            ral[i] = *(const f16x8*)(Al + (size_t)(row0 + r) * K + k0 + off);
        }
        {
            int r = t >> 2, off = (t & 3) * 8;
            rbh = *(const f16x8*)(Bh + (size_t)(col0 + r) * K + k0 + off);
            rbl = *(const f16x8*)(Bl + (size_t)(col0 + r) * K + k0 + off);
        }
        __syncthreads();
#pragma unroll
        for (int i = 0; i < AC; ++i) {
            int idx = t + 256 * i;
            int r = idx >> 2, off = (idx & 3) * 8;
            *(f16x8*)&sAh[r * 40 + off] = rah[i];
            *(f16x8*)&sAl[r * 40 + off] = ral[i];
        }
        {
            int r = t >> 2, off = (t & 3) * 8;
            *(f16x8*)&sBh[r * 40 + off] = rbh;
            *(f16x8*)&sBl[r * 40 + off] = rbl;
        }
        __syncthreads();
        f16x8 fah[4], fal[4], fbh[NT], fbl[NT];
#pragma unroll
        for (int i = 0; i < 4; ++i) {
            fah[i] = *(const f16x8*)&sAh[(m0w + i * 16 + col) * 40 + quad * 8];
            fal[i] = *(const f16x8*)&sAl[(m0w + i * 16 + col) * 40 + quad * 8];
        }
#pragma unroll
        for (int j = 0; j < NT; ++j) {
            fbh[j] = *(const f16x8*)&sBh[(n0w + j * 16 + col) * 40 + quad * 8];
            fbl[j] = *(const f16x8*)&sBl[(n0w + j * 16 + col) * 40 + quad * 8];
        }
#pragma unroll
        for (int i = 0; i < 4; ++i)
#pragma unroll
            for (int j = 0; j < NT; ++j) {
                acc[i][j] = __builtin_amdgcn_mfma_f32_16x16x32_f16(fah[i], fbh[j], acc[i][j], 0, 0, 0);
                acc[i][j] = __builtin_amdgcn_mfma_f32_16x16x32_f16(fah[i], fbl[j], acc[i][j], 0, 0, 0);
                acc[i][j] = __builtin_amdgcn_mfma_f32_16x16x32_f16(fal[i], fbh[j], acc[i][j], 0, 0, 0);
            }
    }
#pragma unroll
    for (int i = 0; i < 4; ++i)
#pragma unroll
        for (int j = 0; j < NT; ++j) {
            int n = col0 + n0w + j * 16 + col;
            int mb = row0 + m0w + i * 16 + quad * 4;
            if (mode == EPI_F32) {
                float bv = bias ? bias[n] : 0.f;
#pragma unroll
                for (int r = 0; r < 4; ++r)
                    Cf[(size_t)(mb + r) * Nc + n] = acc[i][j][r] + bv;
            } else if (mode == EPI_QK) {
#pragma unroll
                for (int r = 0; r < 4; ++r) {
                    hl16 s = split2(acc[i][j][r] * scl);
                    Ch[(size_t)(mb + r) * Nc + n] = s.h;
                    Cl[(size_t)(mb + r) * Nc + n] = s.l;
                }
            } else {  // EPI_VT: [b][h][d][token]
                int b = mb >> 11, token = mb & 2047;
                int h = n >> 5, d = n & 31;
                f16x4 h4, l4;
#pragma unroll
                for (int r = 0; r < 4; ++r) {
                    hl16 s = split2(acc[i][j][r]);
                    h4[r] = s.h;
                    l4[r] = s.l;
                }
                size_t dst = ((size_t)(b * HH + h) * DH + d) * NN + token;
                *(f16x4*)&Ch[dst] = h4;
                *(f16x4*)&Cl[dst] = l4;
            }
        }
}

template <int TM>
__global__ __launch_bounds__(256) void gemm_h_k(const _Float16* __restrict__ Ah,
                                                const _Float16* __restrict__ Al,
                                                const _Float16* __restrict__ Bh,
                                                const _Float16* __restrict__ Bl,
                                                const float* __restrict__ bias,
                                                float* __restrict__ Cf, int Nc, int K) {
    __shared__ _Float16 sAh[TM * 40], sAl[TM * 40], sBh[64 * 40], sBl[64 * 40];
    gemm_h_body<TM>(Ah, Al, Bh, Bl, bias, Cf, nullptr, nullptr, Nc, K,
                    blockIdx.y * TM, blockIdx.x * 64, EPI_F32, 1.f, sAh, sAl, sBh, sBl);
}

// Fused QKV: blockIdx.x in [0,12): mat = x>>2, col block = x&3.
// Q scale folds 1/sqrt(dh) AND log2(e) (softmax uses exp2).
__global__ __launch_bounds__(256) void qkv_h_k(const _Float16* __restrict__ Xh,
                                               const _Float16* __restrict__ Xl,
                                               const _Float16* __restrict__ wt, int layer,
                                               _Float16* Qh, _Float16* Ql,
                                               _Float16* Kh, _Float16* Kl,
                                               _Float16* Vh, _Float16* Vl) {
    __shared__ _Float16 sAh[128 * 40], sAl[128 * 40], sBh[64 * 40], sBl[64 * 40];
    int mat = blockIdx.x >> 2;
    int slot = (layer * 4 + mat) * 2;
    const _Float16* Bh = wt + (size_t)slot * WT_SLOT;
    const _Float16* Bl = wt + (size_t)(slot + 1) * WT_SLOT;
    _Float16* Ch = mat == 0 ? Qh : mat == 1 ? Kh : Vh;
    _Float16* Cl = mat == 0 ? Ql : mat == 1 ? Kl : Vl;
    int mode = (mat == 2) ? EPI_VT : EPI_QK;
    float scl = (mat == 0) ? 0.25501654859214384f : 1.f;  // 1/sqrt(32)*log2(e)
    gemm_h_body<128>(Xh, Xl, Bh, Bl, nullptr, nullptr, Ch, Cl, CC, CC,
                     blockIdx.y * 128, (blockIdx.x & 3) * 64, mode, scl, sAh, sAl, sBh, sBl);
}

// ---------------------------------------------------------------------------
// Attention v4: 64-key tiles, pre-split fp16, 64 q/block (16/wave).
// Scores already in log2 space (scale*log2e folded into Q) -> exp2f softmax.
__global__ __launch_bounds__(256) void attn4_k(_Float16* QOh, _Float16* QOl,
                                               const _Float16* __restrict__ Kh,
                                               const _Float16* __restrict__ Kl,
                                               const _Float16* __restrict__ Vh,
                                               const _Float16* __restrict__ Vl) {
    __shared__ _Float16 sKh[64 * 40], sKl[64 * 40];   // [key][d]
    __shared__ _Float16 sVh[32 * 72], sVl[32 * 72];   // [d][key]
    __shared__ _Float16 sPh[4][16 * 72], sPl[4][16 * 72];  // per-wave [q][key]
    int t = threadIdx.x, w = t >> 6, lane = t & 63;
    int col = lane & 15, quad = lane >> 4;
    int bh = blockIdx.y, b = bh >> 3, h = bh & 7;
    int qbase = blockIdx.x * 64 + w * 16;

    size_t qoff = ((size_t)(b * NN + qbase + col)) * CC + h * DH + quad * 8;
    f16x8 qh = *(const f16x8*)(QOh + qoff);
    f16x8 ql = *(const f16x8*)(QOl + qoff);

    f32x4 o0 = {0.f, 0.f, 0.f, 0.f}, o1 = {0.f, 0.f, 0.f, 0.f};
    float mrun = -1e30f, lsum = 0.f;

    // staging: t<128 -> hi planes, t>=128 -> lo planes. 32B per thread per tensor.
    int pidx = t & 127;
    int krow = pidx >> 1, koff = (pidx & 1) * 16;   // K: [key][d], 64x32 halves
    int vrow = pidx >> 2, voff = (pidx & 3) * 16;   // V: [d][key], 32x64 halves
    const _Float16* kg = (t < 128 ? Kh : Kl) + (size_t)b * NN * CC + h * DH;
    const _Float16* vg = (t < 128 ? Vh : Vl) + ((size_t)(b * HH + h) * DH + vrow) * NN;
    _Float16* dK = (t < 128 ? sKh : sKl) + krow * 40 + koff;
    _Float16* dV = (t < 128 ? sVh : sVl) + vrow * 72 + voff;

    for (int k0 = 0; k0 < NN; k0 += 64) {
        const _Float16* kp = kg + (size_t)(k0 + krow) * CC + koff;
        f16x8 rk0 = *(const f16x8*)kp;
        f16x8 rk1 = *(const f16x8*)(kp + 8);
        const _Float16* vp = vg + k0 + voff;
        f16x8 rv0 = *(const f16x8*)vp;
        f16x8 rv1 = *(const f16x8*)(vp + 8);
        __syncthreads();  // previous tile fully consumed
        *(f16x8*)dK = rk0;
        *(f16x8*)(dK + 8) = rk1;
        *(f16x8*)dV = rv0;
        *(f16x8*)(dV + 8) = rv1;
        __syncthreads();

        // ---- QK^T (S^T = K·Q^T): 4 key subtiles ----
        f32x4 s[4];
#pragma unroll
        for (int kt = 0; kt < 4; ++kt) {
            f16x8 ka = *(const f16x8*)&sKh[(kt * 16 + col) * 40 + quad * 8];
            f16x8 kb = *(const f16x8*)&sKl[(kt * 16 + col) * 40 + quad * 8];
            f32x4 z = {0.f, 0.f, 0.f, 0.f};
            z = __builtin_amdgcn_mfma_f32_16x16x32_f16(ka, qh, z, 0, 0, 0);
            z = __builtin_amdgcn_mfma_f32_16x16x32_f16(ka, ql, z, 0, 0, 0);
            z = __builtin_amdgcn_mfma_f32_16x16x32_f16(kb, qh, z, 0, 0, 0);
            s[kt] = z;
        }

        // ---- online softmax over 64 keys (16 vals/lane + cross-quad shfl) ----
        float tm = -1e30f;
#pragma unroll
        for (int kt = 0; kt < 4; ++kt)
#pragma unroll
            for (int r = 0; r < 4; ++r) tm = fmaxf(tm, s[kt][r]);
        tm = fmaxf(tm, __shfl_xor(tm, 16));
        tm = fmaxf(tm, __shfl_xor(tm, 32));
        float nm = fmaxf(mrun, tm);
        float alpha = exp2f(mrun - nm);
        float p[16], rs = 0.f;
#pragma unroll
        for (int kt = 0; kt < 4; ++kt)
#pragma unroll
            for (int r = 0; r < 4; ++r) {
                float pv = exp2f(s[kt][r] - nm);
                p[kt * 4 + r] = pv;
                rs += pv;
            }
        rs += __shfl_xor(rs, 16);
        rs += __shfl_xor(rs, 32);
        lsum = lsum * alpha + rs;
        mrun = nm;
        o0.x *= alpha; o0.y *= alpha; o0.z *= alpha; o0.w *= alpha;
        o1.x *= alpha; o1.y *= alpha; o1.z *= alpha; o1.w *= alpha;

        // ---- P split + per-wave LDS transpose ([q][key 0..63]) ----
#pragma unroll
        for (int kt = 0; kt < 4; ++kt) {
            f16x4 h4, l4;
#pragma unroll
            for (int r = 0; r < 4; ++r) {
                hl16 sp = split2(p[kt * 4 + r]);
                h4[r] = sp.h;
                l4[r] = sp.l;
            }
            *(f16x4*)&sPh[w][col * 72 + kt * 16 + quad * 4] = h4;
            *(f16x4*)&sPl[w][col * 72 + kt * 16 + quad * 4] = l4;
        }
        __asm__ volatile("s_waitcnt lgkmcnt(0)" ::: "memory");
        f16x8 pH[2], pL[2];
#pragma unroll
        for (int c = 0; c < 2; ++c) {
            pH[c] = *(const f16x8*)&sPh[w][col * 72 + c * 32 + quad * 8];
            pL[c] = *(const f16x8*)&sPl[w][col * 72 + c * 32 + quad * 8];
        }

        // ---- PV: O^T += V^T · P^T (2 key chunks × 2 d-halves) ----
#pragma unroll
        for (int c = 0; c < 2; ++c) {
            f16x8 va = *(const f16x8*)&sVh[col * 72 + c * 32 + quad * 8];
            f16x8 vb = *(const f16x8*)&sVl[col * 72 + c * 32 + quad * 8];
            o0 = __builtin_amdgcn_mfma_f32_16x16x32_f16(va, pH[c], o0, 0, 0, 0);
            o0 = __builtin_amdgcn_mfma_f32_16x16x32_f16(va, pL[c], o0, 0, 0, 0);
            o0 = __builtin_amdgcn_mfma_f32_16x16x32_f16(vb, pH[c], o0, 0, 0, 0);
            f16x8 vc = *(const f16x8*)&sVh[(16 + col) * 72 + c * 32 + quad * 8];
            f16x8 vd = *(const f16x8*)&sVl[(16 + col) * 72 + c * 32 + quad * 8];
            o1 = __builtin_amdgcn_mfma_f32_16x16x32_f16(vc, pH[c], o1, 0, 0, 0);
            o1 = __builtin_amdgcn_mfma_f32_16x16x32_f16(vc, pL[c], o1, 0, 0, 0);
            o1 = __builtin_amdgcn_mfma_f32_16x16x32_f16(vd, pH[c], o1, 0, 0, 0);
        }
    }

    // epilogue: O^T layout col=q, row=d. Write split O into Q buffer (own tokens).
    float inv = 1.f / lsum;
    f32x4 oo[2] = {o0, o1};
#pragma unroll
    for (int dh = 0; dh < 2; ++dh) {
        f16x4 h4, l4;
#pragma unroll
        for (int r = 0; r < 4; ++r) {
            hl16 s = split2(oo[dh][r] * inv);
            h4[r] = s.h;
            l4[r] = s.l;
        }
        size_t dsti = ((size_t)(b * NN + qbase + col)) * CC + h * DH + dh * 16 + quad * 4;
        *(f16x4*)&QOh[dsti] = h4;
        *(f16x4*)&QOl[dsti] = l4;
    }
}

// ---------------------------------------------------------------------------
__global__ __launch_bounds__(256) void add_ln_k(float* __restrict__ X,
                                                const float* __restrict__ P,
                                                const float* __restrict__ g,
                                                const float* __restrict__ bta,
                                                _Float16* __restrict__ Xh,
                                                _Float16* __restrict__ Xl) {
    int wave = threadIdx.x >> 6, lane = threadIdx.x & 63;
    size_t row = (size_t)blockIdx.x * 4 + wave;
    size_t base = row * CC + lane * 4;
    float4 x = *(float4*)(X + base);
    float4 p = *(const float4*)(P + base);
    x.x += p.x; x.y += p.y; x.z += p.z; x.w += p.w;
    float sum = x.x + x.y + x.z + x.w;
    float ss = x.x * x.x + x.y * x.y + x.z * x.z + x.w * x.w;
#pragma unroll
    for (int off = 32; off; off >>= 1) {
        sum += __shfl_down(sum, off);
        ss += __shfl_down(ss, off);
    }
    sum = __shfl(sum, 0);
    ss = __shfl(ss, 0);
    float mean = sum * (1.f / 256.f);
    float var = ss * (1.f / 256.f) - mean * mean;
    float wn = rsqrtf(var + EPSV);
    float4 gg = *(const float4*)(g + lane * 4);
    float4 bb = *(const float4*)(bta + lane * 4);
    x.x = (x.x - mean) * wn * gg.x + bb.x;
    x.y = (x.y - mean) * wn * gg.y + bb.y;
    x.z = (x.z - mean) * wn * gg.z + bb.z;
    x.w = (x.w - mean) * wn * gg.w + bb.w;
    *(float4*)(X + base) = x;
    f16x4 h4, l4;
    float xv[4] = {x.x, x.y, x.z, x.w};
#pragma unroll
    for (int j = 0; j < 4; ++j) {
        hl16 s = split2(xv[j]);
        h4[j] = s.h;
        l4[j] = s.l;
    }
    *(f16x4*)&Xh[base] = h4;
    *(f16x4*)&Xl[base] = l4;
}

// ---------------------------------------------------------------------------
__global__ __launch_bounds__(256) void bn_stats_k(const float* __restrict__ Hm,
                                                  float* __restrict__ stats,
                                                  int M, int Cc) {
    int c = blockIdx.x;
    int t = threadIdx.x;
    float s = 0.f, ss = 0.f;
    for (int r = t; r < M; r += 256) {
        float v = Hm[(size_t)r * Cc + c];
        s += v;
        ss += v * v;
    }
    __shared__ float sh0[256], sh1[256];
    sh0[t] = s; sh1[t] = ss;
    __syncthreads();
    for (int st = 128; st; st >>= 1) {
        if (t < st) { sh0[t] += sh0[t + st]; sh1[t] += sh1[t + st]; }
        __syncthreads();
    }
    if (t == 0) {
        float mean = sh0[0] / (float)M;
        stats[c] = mean;
        stats[Cc + c] = sh1[0] / (float)M - mean * mean;
    }
}

__global__ __launch_bounds__(256) void bn_apply_k(const float* __restrict__ in,
                                                  float* __restrict__ out,
                                                  const float* __restrict__ stats,
                                                  const float* __restrict__ gam,
                                                  const float* __restrict__ bet,
                                                  int total, int Cc, float alpha) {
    int i = blockIdx.x * 256 + threadIdx.x;
    if (i >= total) return;
    int c = i % Cc;
    float v = (in[i] - stats[c]) * rsqrtf(stats[Cc + c] + EPSV) * gam[c] + bet[c];
    out[i] = v > 0.f ? v : alpha * v;
}

__global__ __launch_bounds__(256) void bn_apply_split_k(const float* __restrict__ in,
                                                        _Float16* __restrict__ oh,
                                                        _Float16* __restrict__ ol,
                                                        const float* __restrict__ stats,
                                                        const float* __restrict__ gam,
                                                        const float* __restrict__ bet,
                                                        int total, int Cc, float alpha) {
    int i = blockIdx.x * 256 + threadIdx.x;
    if (i >= total) return;
    int c = i % Cc;
    float v = (in[i] - stats[c]) * rsqrtf(stats[Cc + c] + EPSV) * gam[c] + bet[c];
    v = v > 0.f ? v : alpha * v;
    hl16 s = split2(v);
    oh[i] = s.h;
    ol[i] = s.l;
}

// ---------------------------------------------------------------------------
__global__ __launch_bounds__(64) void select_k(const float* __restrict__ H3,
                                               const float* __restrict__ pts,
                                               float* __restrict__ G0) {
    int bs = blockIdx.x;
    int b = bs >> 4, ch = bs & 15;
    int lane = threadIdx.x;
    float best = -1e30f;
    int bn = 0;
    for (int n = lane; n < NN; n += 64) {
        float v = H3[((size_t)(b * NN + n)) * 16 + ch];
        if (v > best) { best = v; bn = n; }
    }
#pragma unroll
    for (int off = 32; off; off >>= 1) {
        float ov = __shfl_xor(best, off);
        int on = __shfl_xor(bn, off);
        if (ov > best || (ov == best && on < bn)) { best = ov; bn = on; }
    }
    const float* px = pts + (size_t)b * 3 * NN;
    float qx = px[bn], qy = px[NN + bn], qz = px[2 * NN + bn];
    float qq = (qx * qx + qy * qy) + qz * qz;
    __shared__ int sgi[NSAMPLE];
    const float R2 = 0.09f;
    int cnt = 0;
    for (int base = 0; base < NN && cnt < NSAMPLE; base += 64) {
        int n = base + lane;
        float x = px[n], y = px[NN + n], z = px[2 * NN + n];
        float pp = (x * x + y * y) + z * z;
        float dot = (qx * x + qy * y) + qz * z;
        float sqd = (qq + pp) - 2.f * dot;
        bool ok = !(sqd > R2);
        unsigned long long mk = __ballot(ok);
        int pos = cnt + (int)__popcll(mk & ((1ull << lane) - 1ull));
        if (ok && pos < NSAMPLE) sgi[pos] = n;
        cnt += (int)__popcll(mk);
    }
    __syncthreads();
    int g0 = sgi[0];
    if (lane >= cnt && lane < NSAMPLE) sgi[lane] = g0;
    __syncthreads();
    for (int e = lane; e < KK * 3; e += 64) {
        int k = e / 3, d = e % 3;
        int src = (k == 0) ? bn : sgi[k - 1];
        G0[((size_t)bs * KK + k) * 3 + d] = px[d * NN + src];
    }
}

// ---------------------------------------------------------------------------
__global__ __launch_bounds__(256) void maxpool_k(const float* __restrict__ G3,
                                                 float* __restrict__ out) {
    int i = blockIdx.x * 256 + threadIdx.x;
    if (i >= BB * 512 * SS) return;
    int o = i & 511;
    int s = (i >> 9) & 15;
    int b = i >> 13;
    const float* p = G3 + ((size_t)(b * SS + s) * KK) * 512 + o;
    float mx = p[0];
#pragma unroll
    for (int k = 1; k < KK; ++k) mx = fmaxf(mx, p[(size_t)k * 512]);
    out[((size_t)(b * 512 + o)) * SS + s] = mx;
}

// ---------------------------------------------------------------------------
extern "C" void kernel_launch(void* const* d_in, const int* in_sizes, int n_in,
                              void* d_out, int out_size, void* d_ws, size_t ws_size,
                              hipStream_t stream) {
    const float* hoch = (const float*)d_in[0];
    const float* pts = (const float*)d_in[1];
    const float* Wq = (const float*)d_in[2];
    const float* Wk = (const float*)d_in[3];
    const float* Wv = (const float*)d_in[4];
    const float* Wo = (const float*)d_in[5];
    const float* ln_g = (const float*)d_in[6];
    const float* ln_b = (const float*)d_in[7];
    const float* fg_w1 = (const float*)d_in[8];
    const float* fg_b1 = (const float*)d_in[9];
    const float* fg_w2 = (const float*)d_in[10];
    const float* fg_b2 = (const float*)d_in[11];
    const float* fg_w3 = (const float*)d_in[12];
    const float* fg_b3 = (const float*)d_in[13];
    const float* fg_g1 = (const float*)d_in[14];
    const float* fg_be1 = (const float*)d_in[15];
    const float* fg_g2 = (const float*)d_in[16];
    const float* fg_be2 = (const float*)d_in[17];
    const float* fg_g3 = (const float*)d_in[18];
    const float* fg_be3 = (const float*)d_in[19];
    const float* cw1 = (const float*)d_in[20];
    const float* cw2 = (const float*)d_in[21];
    const float* cw3 = (const float*)d_in[22];
    const float* cg1 = (const float*)d_in[23];
    const float* cb1 = (const float*)d_in[24];
    const float* cg2 = (const float*)d_in[25];
    const float* cb2 = (const float*)d_in[26];
    const float* cg3 = (const float*)d_in[27];
    const float* cb3 = (const float*)d_in[28];
    float* out = (float*)d_out;

    float* ws = (float*)d_ws;
    const size_t M1 = (size_t)BB * NN * CC;  // 2,097,152
    float* X = ws;
    float* bA = ws + M1;
    float* bB = ws + 2 * M1;
    float* bC = ws + 3 * M1;
    _Float16* hb = (_Float16*)(ws + 4 * M1);
    _Float16* Xh = hb;
    _Float16* Xl = hb + M1;
    _Float16* Qh = hb + 2 * M1;  // also O (attn writes split O back here)
    _Float16* Ql = hb + 3 * M1;
    _Float16* Kh = hb + 4 * M1;  // also conv activations post-transformer
    _Float16* Kl = hb + 5 * M1;
    _Float16* Vh = hb + 6 * M1;
    _Float16* Vl = hb + 7 * M1;
    _Float16* wt = hb + 8 * M1;  // 1,376,256 halves
    float* sm = ws + 4 * M1 + (9 * M1) / 2;
    float* stats = sm;        // 1024
    float* G0 = sm + 1024;    // 6336

    prep_split_k<<<2688, 256, 0, stream>>>(Wq, Wk, Wv, Wo, fg_w1, cw2, cw3, wt);
    transpose_split_k<<<dim3(NN / 32, CC / 32, BB), dim3(32, 8), 0, stream>>>(hoch, X, Xh, Xl);

    const int Mrows = BB * NN;  // 8192
    for (int l = 0; l < LL; ++l) {
        qkv_h_k<<<dim3(12, Mrows / 128), 256, 0, stream>>>(Xh, Xl, wt, l, Qh, Ql, Kh, Kl, Vh, Vl);
        attn4_k<<<dim3(NN / 64, BB * HH), 256, 0, stream>>>(Qh, Ql, Kh, Kl, Vh, Vl);
        int slot = (l * 4 + 3) * 2;
        gemm_h_k<128><<<dim3(CC / 64, Mrows / 128), 256, 0, stream>>>(
            Qh, Ql, wt + (size_t)slot * WT_SLOT, wt + (size_t)(slot + 1) * WT_SLOT,
            nullptr, bA, CC, CC);
        add_ln_k<<<Mrows / 4, 256, 0, stream>>>(X, bA, ln_g + l * CC, ln_b + l * CC, Xh, Xl);
    }

    // fg head: 256 -> 64 -> 32 -> 16, BN+ReLU each
    gemm_h_k<64><<<dim3(1, Mrows / 64), 256, 0, stream>>>(Xh, Xl, wt + FG1H_OFF, wt + FG1L_OFF, fg_b1, bA, 64, 256);
    bn_stats_k<<<64, 256, 0, stream>>>(bA, stats, Mrows, 64);
    bn_apply_k<<<(Mrows * 64 + 255) / 256, 256, 0, stream>>>(bA, bA, stats, fg_g1, fg_be1, Mrows * 64, 64, 0.f);
    gemm_k<true, true><<<dim3(1, Mrows / 64), 256, 0, stream>>>(bA, fg_w2, fg_b2, bB, Mrows, 32, 64);
    bn_stats_k<<<32, 256, 0, stream>>>(bB, stats, Mrows, 32);
    bn_apply_k<<<(Mrows * 32 + 255) / 256, 256, 0, stream>>>(bB, bB, stats, fg_g2, fg_be2, Mrows * 32, 32, 0.f);
    gemm_k<true, true><<<dim3(1, Mrows / 64), 256, 0, stream>>>(bB, fg_w3, fg_b3, bC, Mrows, 16, 32);
    bn_stats_k<<<16, 256, 0, stream>>>(bC, stats, Mrows, 16);
    bn_apply_k<<<(Mrows * 16 + 255) / 256, 256, 0, stream>>>(bC, bC, stats, fg_g3, fg_be3, Mrows * 16, 16, 0.f);

    // selection + grouping (fused)
    select_k<<<BB * SS, 64, 0, stream>>>(bC, pts, G0);

    // conv stack: 3 -> 64 -> 256 -> 512, BN+LeakyReLU(0.2)
    const int Mg = BB * SS * KK;  // 2112 = 33*64
    gemm_k<true, false><<<dim3(1, Mg / 64), 256, 0, stream>>>(G0, cw1, nullptr, bA, Mg, 64, 3);
    bn_stats_k<<<64, 256, 0, stream>>>(bA, stats, Mg, 64);
    bn_apply_split_k<<<(Mg * 64 + 255) / 256, 256, 0, stream>>>(bA, Kh, Kl, stats, cg1, cb1, Mg * 64, 64, 0.2f);
    gemm_h_k<64><<<dim3(4, Mg / 64), 256, 0, stream>>>(Kh, Kl, wt + CW2H_OFF, wt + CW2L_OFF, nullptr, bB, 256, 64);
    bn_stats_k<<<256, 256, 0, stream>>>(bB, stats, Mg, 256);
    bn_apply_split_k<<<(Mg * 256 + 255) / 256, 256, 0, stream>>>(bB, Kh, Kl, stats, cg2, cb2, Mg * 256, 256, 0.2f);
    gemm_h_k<64><<<dim3(8, Mg / 64), 256, 0, stream>>>(Kh, Kl, wt + CW3H_OFF, wt + CW3L_OFF, nullptr, bC, 512, 256);
    bn_stats_k<<<512, 256, 0, stream>>>(bC, stats, Mg, 512);
    bn_apply_k<<<(Mg * 512 + 255) / 256, 256, 0, stream>>>(bC, bC, stats, cg3, cb3, Mg * 512, 512, 0.2f);

    maxpool_k<<<(BB * 512 * SS + 255) / 256, 256, 0, stream>>>(bC, out);

    (void)in_sizes; (void)n_in; (void)out_size; (void)ws_size;
}

// Round 8
// 456.591 us; speedup vs baseline: 5.4319x; 1.1747x over previous
//
#include <hip/hip_runtime.h>
#include <hip/hip_bf16.h>
#include <math.h>

// Problem constants
#define BB 4
#define NN 2048
#define CC 256
#define HH 8
#define DH 32
#define LL 2
#define SS 16
#define KK 33
#define NSAMPLE 32
#define EPSV 1e-5f

typedef _Float16 f16x8 __attribute__((ext_vector_type(8)));
typedef _Float16 f16x4 __attribute__((ext_vector_type(4)));
typedef float f32x4 __attribute__((ext_vector_type(4)));

struct hl16 { _Float16 h, l; };
__device__ __forceinline__ hl16 split2(float v) {
    hl16 r;
    r.h = (_Float16)v;
    r.l = (_Float16)(v - (float)r.h);
    return r;
}

#define INV_MF (1.f / 8192.f)
#define INV_MG (1.f / 2112.f)

// Pre-split weight table offsets (in halves)
#define WT_SLOT 65536
#define FG1H_OFF 1048576
#define FG1L_OFF (FG1H_OFF + 16384)
#define CW2H_OFF (FG1H_OFF + 32768)
#define CW2L_OFF (FG1H_OFF + 49152)
#define CW3H_OFF (FG1H_OFF + 65536)
#define CW3L_OFF (CW3H_OFF + 131072)

// ---------------------------------------------------------------------------
// One-time: zero stats regions + split all MFMA-path weights to fp16 hi/lo.
__global__ __launch_bounds__(256) void prep_split_k(
    const float* __restrict__ Wq, const float* __restrict__ Wk,
    const float* __restrict__ Wv, const float* __restrict__ Wo,
    const float* __restrict__ fgw1, const float* __restrict__ cw2,
    const float* __restrict__ cw3, _Float16* __restrict__ wt,
    float* __restrict__ stats0) {
    int e = blockIdx.x * 256 + threadIdx.x;
    if (e < 6144) stats0[e] = 0.f;
    if (e < 524288) {
        int slot = e >> 16;  // l*4 + mat
        int l = slot >> 2, mat = slot & 3;
        int r = e & 65535;
        int n = r >> 8, k = r & 255;
        const float* W = mat == 0 ? Wq : mat == 1 ? Wk : mat == 2 ? Wv : Wo;
        hl16 s = split2(W[(size_t)l * 65536 + k * 256 + n]);
        wt[(size_t)(2 * slot) * WT_SLOT + n * 256 + k] = s.h;
        wt[(size_t)(2 * slot + 1) * WT_SLOT + n * 256 + k] = s.l;
    } else if (e < 524288 + 16384) {
        int r = e - 524288;
        hl16 s = split2(fgw1[r]);
        wt[FG1H_OFF + r] = s.h;
        wt[FG1L_OFF + r] = s.l;
    } else if (e < 524288 + 32768) {
        int r = e - (524288 + 16384);
        hl16 s = split2(cw2[r]);
        wt[CW2H_OFF + r] = s.h;
        wt[CW2L_OFF + r] = s.l;
    } else if (e < 524288 + 32768 + 131072) {
        int r = e - (524288 + 32768);
        hl16 s = split2(cw3[r]);
        wt[CW3H_OFF + r] = s.h;
        wt[CW3L_OFF + r] = s.l;
    }
}

// ---------------------------------------------------------------------------
__global__ __launch_bounds__(256) void transpose_split_k(const float* __restrict__ in,
                                                         float* __restrict__ out,
                                                         _Float16* __restrict__ oh,
                                                         _Float16* __restrict__ ol) {
    __shared__ float tls[32][33];
    int n0 = blockIdx.x * 32, c0 = blockIdx.y * 32, b = blockIdx.z;
    const float* ip = in + (size_t)b * CC * NN;
    size_t ob = (size_t)b * NN * CC;
    int tx = threadIdx.x, ty = threadIdx.y;
#pragma unroll
    for (int i = 0; i < 4; ++i)
        tls[ty + i * 8][tx] = ip[(size_t)(c0 + ty + i * 8) * NN + n0 + tx];
    __syncthreads();
#pragma unroll
    for (int i = 0; i < 4; ++i) {
        size_t oi = ob + (size_t)(n0 + ty + i * 8) * CC + c0 + tx;
        float v = tls[tx][ty + i * 8];
        out[oi] = v;
        hl16 s = split2(v);
        oh[oi] = s.h;
        ol[oi] = s.l;
    }
}

// ---------------------------------------------------------------------------
// fp32 GEMM with optional fused input-BN+ReLU (staging) and output-stats.
// pst: raw sums of A's channels ([c], [K+c]); ost: raw-sum accumulation for C.
template <bool TRANSB, bool BIAS>
__global__ __launch_bounds__(256) void gemm_k(const float* __restrict__ A,
                                              const float* __restrict__ Bm,
                                              const float* __restrict__ bias,
                                              float* __restrict__ Cm,
                                              int M, int Nc, int K,
                                              const float* __restrict__ pst,
                                              const float* __restrict__ pg,
                                              const float* __restrict__ pb,
                                              float pInvM,
                                              float* __restrict__ ost) {
    __shared__ float As[16][68];
    __shared__ float Bs[16][68];
    __shared__ float sSc[64], sSh[64];
    int t = threadIdx.x;
    int tx = t & 15, ty = t >> 4;
    int row0 = blockIdx.y * 64, col0 = blockIdx.x * 64;
    if (pst && t < K) {
        float mean = pst[t] * pInvM;
        float var = pst[K + t] * pInvM - mean * mean;
        float wv = rsqrtf(var + EPSV) * pg[t];
        sSc[t] = wv;
        sSh[t] = pb[t] - mean * wv;
    }
    if (pst) __syncthreads();
    float acc[4][4] = {};
    for (int k0 = 0; k0 < K; k0 += 16) {
#pragma unroll
        for (int p = 0; p < 4; ++p) {
            int i = t + 256 * p;
            int m = i >> 4, k = i & 15;
            int gm = row0 + m, gk = k0 + k;
            float av = 0.f;
            if (gm < M && gk < K) {
                av = A[(size_t)gm * K + gk];
                if (pst) {
                    av = fmaf(av, sSc[gk], sSh[gk]);
                    av = fmaxf(av, 0.f);
                }
            }
            As[k][m] = av;
        }
#pragma unroll
        for (int p = 0; p < 4; ++p) {
            int i = t + 256 * p;
            if (TRANSB) {
                int k = i & 15, n = i >> 4;
                int gn = col0 + n, gk = k0 + k;
                Bs[k][n] = (gn < Nc && gk < K) ? Bm[(size_t)gn * K + gk] : 0.f;
            } else {
                int n = i & 63, k = i >> 6;
                int gn = col0 + n, gk = k0 + k;
                Bs[k][n] = (gn < Nc && gk < K) ? Bm[(size_t)gk * Nc + gn] : 0.f;
            }
        }
        __syncthreads();
#pragma unroll
        for (int kk = 0; kk < 16; ++kk) {
            float4 a4 = *(const float4*)&As[kk][ty * 4];
            float4 b4 = *(const float4*)&Bs[kk][tx * 4];
            float av[4] = {a4.x, a4.y, a4.z, a4.w};
            float bv[4] = {b4.x, b4.y, b4.z, b4.w};
#pragma unroll
            for (int i = 0; i < 4; ++i)
#pragma unroll
                for (int j = 0; j < 4; ++j) acc[i][j] = fmaf(av[i], bv[j], acc[i][j]);
        }
        __syncthreads();
    }
    float cs[4] = {}, css[4] = {};
#pragma unroll
    for (int i = 0; i < 4; ++i) {
        int r = row0 + ty * 4 + i;
        if (r >= M) continue;
#pragma unroll
        for (int j = 0; j < 4; ++j) {
            int c = col0 + tx * 4 + j;
            if (c >= Nc) continue;
            float v = acc[i][j];
            if (BIAS) v += bias[c];
            Cm[(size_t)r * Nc + c] = v;
            cs[j] += v;
            css[j] += v * v;
        }
    }
    if (ost) {
        float* sc = &As[0][0];  // 128 floats scratch
        if (t < 128) sc[t] = 0.f;
        __syncthreads();
#pragma unroll
        for (int j = 0; j < 4; ++j) {
            atomicAdd(&sc[tx * 4 + j], cs[j]);
            atomicAdd(&sc[64 + tx * 4 + j], css[j]);
        }
        __syncthreads();
        if (t < Nc) atomicAdd(&ost[t], sc[t]);
        else if (t >= 64 && t - 64 < Nc) atomicAdd(&ost[Nc + t - 64], sc[t]);
    }
}

// ---------------------------------------------------------------------------
// Pre-split fp16 MFMA GEMM. A: Ah/Al [M][K] fp16; B: Bh/Bl [N][K] fp16.
#define EPI_F32 0
#define EPI_QK 1
#define EPI_VT 2

template <int TM>
__device__ __forceinline__ void gemm_h_body(
    const _Float16* __restrict__ Ah, const _Float16* __restrict__ Al,
    const _Float16* __restrict__ Bh, const _Float16* __restrict__ Bl,
    const float* __restrict__ bias, float* __restrict__ Cf,
    _Float16* __restrict__ Ch, _Float16* __restrict__ Cl,
    int Nc, int K, int row0, int col0, int mode, float scl,
    float* __restrict__ ost,
    _Float16* sAh, _Float16* sAl, _Float16* sBh, _Float16* sBl) {
    int t = threadIdx.x, w = t >> 6, lane = t & 63;
    int col = lane & 15, quad = lane >> 4;
    const int m0w = (TM == 128) ? (w & 1) * 64 : 0;
    const int n0w = (TM == 128) ? (w >> 1) * 32 : w * 16;
    constexpr int NT = (TM == 128) ? 2 : 1;
    constexpr int AC = TM / 64;
    f32x4 acc[4][NT];
#pragma unroll
    for (int i = 0; i < 4; ++i)
#pragma unroll
        for (int j = 0; j < NT; ++j) acc[i][j] = (f32x4){0.f, 0.f, 0.f, 0.f};

    for (int k0 = 0; k0 < K; k0 += 32) {
        f16x8 rah[AC], ral[AC], rbh, rbl;
#pragma unroll
        for (int i = 0; i < AC; ++i) {
            int idx = t + 256 * i;
            int r = idx >> 2, off = (idx & 3) * 8;
            rah[i] = *(const f16x8*)(Ah + (size_t)(row0 + r) * K + k0 + off);
            ral[i] = *(const f16x8*)(Al + (size_t)(row0 + r) * K + k0 + off);
        }
        {
            int r = t >> 2, off = (t & 3) * 8;
            rbh = *(const f16x8*)(Bh + (size_t)(col0 + r) * K + k0 + off);
            rbl = *(const f16x8*)(Bl + (size_t)(col0 + r) * K + k0 + off);
        }
        __syncthreads();
#pragma unroll
        for (int i = 0; i < AC; ++i) {
            int idx = t + 256 * i;
            int r = idx >> 2, off = (idx & 3) * 8;
            *(f16x8*)&sAh[r * 40 + off] = rah[i];
            *(f16x8*)&sAl[r * 40 + off] = ral[i];
        }
        {
            int r = t >> 2, off = (t & 3) * 8;
            *(f16x8*)&sBh[r * 40 + off] = rbh;
            *(f16x8*)&sBl[r * 40 + off] = rbl;
        }
        __syncthreads();
        f16x8 fah[4], fal[4], fbh[NT], fbl[NT];
#pragma unroll
        for (int i = 0; i < 4; ++i) {
            fah[i] = *(const f16x8*)&sAh[(m0w + i * 16 + col) * 40 + quad * 8];
            fal[i] = *(const f16x8*)&sAl[(m0w + i * 16 + col) * 40 + quad * 8];
        }
#pragma unroll
        for (int j = 0; j < NT; ++j) {
            fbh[j] = *(const f16x8*)&sBh[(n0w + j * 16 + col) * 40 + quad * 8];
            fbl[j] = *(const f16x8*)&sBl[(n0w + j * 16 + col) * 40 + quad * 8];
        }
#pragma unroll
        for (int i = 0; i < 4; ++i)
#pragma unroll
            for (int j = 0; j < NT; ++j) {
                acc[i][j] = __builtin_amdgcn_mfma_f32_16x16x32_f16(fah[i], fbh[j], acc[i][j], 0, 0, 0);
                acc[i][j] = __builtin_amdgcn_mfma_f32_16x16x32_f16(fah[i], fbl[j], acc[i][j], 0, 0, 0);
                acc[i][j] = __builtin_amdgcn_mfma_f32_16x16x32_f16(fal[i], fbh[j], acc[i][j], 0, 0, 0);
            }
    }
    float s = 0.f, ss = 0.f;
#pragma unroll
    for (int i = 0; i < 4; ++i)
#pragma unroll
        for (int j = 0; j < NT; ++j) {
            int n = col0 + n0w + j * 16 + col;
            int mb = row0 + m0w + i * 16 + quad * 4;
            if (mode == EPI_F32) {
                float bv = bias ? bias[n] : 0.f;
#pragma unroll
                for (int r = 0; r < 4; ++r) {
                    float v = acc[i][j][r] + bv;
                    Cf[(size_t)(mb + r) * Nc + n] = v;
                    s += v;
                    ss += v * v;
                }
            } else if (mode == EPI_QK) {
#pragma unroll
                for (int r = 0; r < 4; ++r) {
                    hl16 sp = split2(acc[i][j][r] * scl);
                    Ch[(size_t)(mb + r) * Nc + n] = sp.h;
                    Cl[(size_t)(mb + r) * Nc + n] = sp.l;
                }
            } else {  // EPI_VT: [b][h][d][token]
                int b = mb >> 11, token = mb & 2047;
                int h = n >> 5, d = n & 31;
                f16x4 h4, l4;
#pragma unroll
                for (int r = 0; r < 4; ++r) {
                    hl16 sp = split2(acc[i][j][r]);
                    h4[r] = sp.h;
                    l4[r] = sp.l;
                }
                size_t dst = ((size_t)(b * HH + h) * DH + d) * NN + token;
                *(f16x4*)&Ch[dst] = h4;
                *(f16x4*)&Cl[dst] = l4;
            }
        }
    if (ost && mode == EPI_F32 && TM == 64) {
        s += __shfl_xor(s, 16);
        s += __shfl_xor(s, 32);
        ss += __shfl_xor(ss, 16);
        ss += __shfl_xor(ss, 32);
        if (quad == 0) {
            int n = col0 + n0w + col;
            atomicAdd(&ost[n], s);
            atomicAdd(&ost[Nc + n], ss);
        }
    }
}

template <int TM>
__global__ __launch_bounds__(256) void gemm_h_k(const _Float16* __restrict__ Ah,
                                                const _Float16* __restrict__ Al,
                                                const _Float16* __restrict__ Bh,
                                                const _Float16* __restrict__ Bl,
                                                const float* __restrict__ bias,
                                                float* __restrict__ Cf, int Nc, int K,
                                                float* __restrict__ ost) {
    __shared__ _Float16 sAh[TM * 40], sAl[TM * 40], sBh[64 * 40], sBl[64 * 40];
    gemm_h_body<TM>(Ah, Al, Bh, Bl, bias, Cf, nullptr, nullptr, Nc, K,
                    blockIdx.y * TM, blockIdx.x * 64, EPI_F32, 1.f, ost,
                    sAh, sAl, sBh, sBl);
}

// Fused QKV: blockIdx.x in [0,12): mat = x>>2, col block = x&3.
// Q scale folds 1/sqrt(dh) AND log2(e) (softmax uses exp2).
__global__ __launch_bounds__(256) void qkv_h_k(const _Float16* __restrict__ Xh,
                                               const _Float16* __restrict__ Xl,
                                               const _Float16* __restrict__ wt, int layer,
                                               _Float16* Qh, _Float16* Ql,
                                               _Float16* Kh, _Float16* Kl,
                                               _Float16* Vh, _Float16* Vl) {
    __shared__ _Float16 sAh[128 * 40], sAl[128 * 40], sBh[64 * 40], sBl[64 * 40];
    int mat = blockIdx.x >> 2;
    int slot = (layer * 4 + mat) * 2;
    const _Float16* Bh = wt + (size_t)slot * WT_SLOT;
    const _Float16* Bl = wt + (size_t)(slot + 1) * WT_SLOT;
    _Float16* Ch = mat == 0 ? Qh : mat == 1 ? Kh : Vh;
    _Float16* Cl = mat == 0 ? Ql : mat == 1 ? Kl : Vl;
    int mode = (mat == 2) ? EPI_VT : EPI_QK;
    float scl = (mat == 0) ? 0.25501654859214384f : 1.f;  // 1/sqrt(32)*log2(e)
    gemm_h_body<128>(Xh, Xl, Bh, Bl, nullptr, nullptr, Ch, Cl, CC, CC,
                     blockIdx.y * 128, (blockIdx.x & 3) * 64, mode, scl, nullptr,
                     sAh, sAl, sBh, sBl);
}

// ---------------------------------------------------------------------------
// Attention v4.1: 64-key tiles, pre-split fp16, 64 q/block (16/wave).
__global__ __launch_bounds__(256) void attn4_k(_Float16* QOh, _Float16* QOl,
                                               const _Float16* __restrict__ Kh,
                                               const _Float16* __restrict__ Kl,
                                               const _Float16* __restrict__ Vh,
                                               const _Float16* __restrict__ Vl) {
    __shared__ _Float16 sKh[64 * 40], sKl[64 * 40];   // [key][d]
    __shared__ _Float16 sVh[32 * 72], sVl[32 * 72];   // [d][key]
    __shared__ _Float16 sPh[4][16 * 72], sPl[4][16 * 72];  // per-wave [q][key]
    int t = threadIdx.x, w = t >> 6, lane = t & 63;
    int col = lane & 15, quad = lane >> 4;
    int bh = blockIdx.y, b = bh >> 3, h = bh & 7;
    int qbase = blockIdx.x * 64 + w * 16;

    size_t qoff = ((size_t)(b * NN + qbase + col)) * CC + h * DH + quad * 8;
    f16x8 qh = *(const f16x8*)(QOh + qoff);
    f16x8 ql = *(const f16x8*)(QOl + qoff);

    f32x4 o0 = {0.f, 0.f, 0.f, 0.f}, o1 = {0.f, 0.f, 0.f, 0.f};
    float mrun = -1e30f, lsum = 0.f;

    // hoisted LDS base pointers
    const _Float16* fKh = &sKh[col * 40 + quad * 8];
    const _Float16* fKl = &sKl[col * 40 + quad * 8];
    const _Float16* fVh0 = &sVh[col * 72 + quad * 8];
    const _Float16* fVl0 = &sVl[col * 72 + quad * 8];
    const _Float16* fVh1 = &sVh[(16 + col) * 72 + quad * 8];
    const _Float16* fVl1 = &sVl[(16 + col) * 72 + quad * 8];
    _Float16* wPh = &sPh[w][col * 72 + quad * 4];
    _Float16* wPl = &sPl[w][col * 72 + quad * 4];
    const _Float16* rPh = &sPh[w][col * 72 + quad * 8];
    const _Float16* rPl = &sPl[w][col * 72 + quad * 8];

    // staging: t<128 -> hi planes, t>=128 -> lo planes. 32B per thread per tensor.
    int pidx = t & 127;
    int krow = pidx >> 1, koff = (pidx & 1) * 16;   // K: [key][d], 64x32 halves
    int vrow = pidx >> 2, voff = (pidx & 3) * 16;   // V: [d][key], 32x64 halves
    const _Float16* kg = (t < 128 ? Kh : Kl) + (size_t)b * NN * CC + h * DH;
    const _Float16* vg = (t < 128 ? Vh : Vl) + ((size_t)(b * HH + h) * DH + vrow) * NN;
    _Float16* dK = (t < 128 ? sKh : sKl) + krow * 40 + koff;
    _Float16* dV = (t < 128 ? sVh : sVl) + vrow * 72 + voff;

    for (int k0 = 0; k0 < NN; k0 += 64) {
        const _Float16* kp = kg + (size_t)(k0 + krow) * CC + koff;
        f16x8 rk0 = *(const f16x8*)kp;
        f16x8 rk1 = *(const f16x8*)(kp + 8);
        const _Float16* vp = vg + k0 + voff;
        f16x8 rv0 = *(const f16x8*)vp;
        f16x8 rv1 = *(const f16x8*)(vp + 8);
        __syncthreads();  // previous tile fully consumed
        *(f16x8*)dK = rk0;
        *(f16x8*)(dK + 8) = rk1;
        *(f16x8*)dV = rv0;
        *(f16x8*)(dV + 8) = rv1;
        __syncthreads();

        // ---- QK^T (S^T = K·Q^T): 4 key subtiles ----
        f32x4 s[4];
#pragma unroll
        for (int kt = 0; kt < 4; ++kt) {
            f16x8 ka = *(const f16x8*)(fKh + kt * 16 * 40);
            f16x8 kb = *(const f16x8*)(fKl + kt * 16 * 40);
            f32x4 z = {0.f, 0.f, 0.f, 0.f};
            z = __builtin_amdgcn_mfma_f32_16x16x32_f16(ka, qh, z, 0, 0, 0);
            z = __builtin_amdgcn_mfma_f32_16x16x32_f16(ka, ql, z, 0, 0, 0);
            z = __builtin_amdgcn_mfma_f32_16x16x32_f16(kb, qh, z, 0, 0, 0);
            s[kt] = z;
        }

        // ---- online softmax over 64 keys ----
        float tm = -1e30f;
#pragma unroll
        for (int kt = 0; kt < 4; ++kt)
#pragma unroll
            for (int r = 0; r < 4; ++r) tm = fmaxf(tm, s[kt][r]);
        tm = fmaxf(tm, __shfl_xor(tm, 16));
        tm = fmaxf(tm, __shfl_xor(tm, 32));
        float nm = fmaxf(mrun, tm);
        float alpha = __builtin_amdgcn_exp2f(mrun - nm);
        float p[16], rs = 0.f;
#pragma unroll
        for (int kt = 0; kt < 4; ++kt)
#pragma unroll
            for (int r = 0; r < 4; ++r) {
                float pv = __builtin_amdgcn_exp2f(s[kt][r] - nm);
                p[kt * 4 + r] = pv;
                rs += pv;
            }
        rs += __shfl_xor(rs, 16);
        rs += __shfl_xor(rs, 32);
        lsum = lsum * alpha + rs;
        mrun = nm;
        o0.x *= alpha; o0.y *= alpha; o0.z *= alpha; o0.w *= alpha;
        o1.x *= alpha; o1.y *= alpha; o1.z *= alpha; o1.w *= alpha;

        // ---- P split + per-wave LDS transpose ([q][key 0..63]) ----
#pragma unroll
        for (int kt = 0; kt < 4; ++kt) {
            f16x4 h4, l4;
#pragma unroll
            for (int r = 0; r < 4; ++r) {
                hl16 sp = split2(p[kt * 4 + r]);
                h4[r] = sp.h;
                l4[r] = sp.l;
            }
            *(f16x4*)(wPh + kt * 16) = h4;
            *(f16x4*)(wPl + kt * 16) = l4;
        }
        __asm__ volatile("s_waitcnt lgkmcnt(0)" ::: "memory");
        f16x8 pH[2], pL[2];
#pragma unroll
        for (int c = 0; c < 2; ++c) {
            pH[c] = *(const f16x8*)(rPh + c * 32);
            pL[c] = *(const f16x8*)(rPl + c * 32);
        }

        // ---- PV: O^T += V^T · P^T (2 key chunks × 2 d-halves) ----
#pragma unroll
        for (int c = 0; c < 2; ++c) {
            f16x8 va = *(const f16x8*)(fVh0 + c * 32);
            f16x8 vb = *(const f16x8*)(fVl0 + c * 32);
            o0 = __builtin_amdgcn_mfma_f32_16x16x32_f16(va, pH[c], o0, 0, 0, 0);
            o0 = __builtin_amdgcn_mfma_f32_16x16x32_f16(va, pL[c], o0, 0, 0, 0);
            o0 = __builtin_amdgcn_mfma_f32_16x16x32_f16(vb, pH[c], o0, 0, 0, 0);
            f16x8 vc = *(const f16x8*)(fVh1 + c * 32);
            f16x8 vd = *(const f16x8*)(fVl1 + c * 32);
            o1 = __builtin_amdgcn_mfma_f32_16x16x32_f16(vc, pH[c], o1, 0, 0, 0);
            o1 = __builtin_amdgcn_mfma_f32_16x16x32_f16(vc, pL[c], o1, 0, 0, 0);
            o1 = __builtin_amdgcn_mfma_f32_16x16x32_f16(vd, pH[c], o1, 0, 0, 0);
        }
    }

    // epilogue: O^T layout col=q, row=d. Write split O into Q buffer (own tokens).
    float inv = 1.f / lsum;
    f32x4 oo[2] = {o0, o1};
#pragma unroll
    for (int dh = 0; dh < 2; ++dh) {
        f16x4 h4, l4;
#pragma unroll
        for (int r = 0; r < 4; ++r) {
            hl16 s = split2(oo[dh][r] * inv);
            h4[r] = s.h;
            l4[r] = s.l;
        }
        size_t dsti = ((size_t)(b * NN + qbase + col)) * CC + h * DH + dh * 16 + quad * 4;
        *(f16x4*)&QOh[dsti] = h4;
        *(f16x4*)&QOl[dsti] = l4;
    }
}

// ---------------------------------------------------------------------------
__global__ __launch_bounds__(256) void add_ln_k(float* __restrict__ X,
                                                const float* __restrict__ P,
                                                const float* __restrict__ g,
                                                const float* __restrict__ bta,
                                                _Float16* __restrict__ Xh,
                                                _Float16* __restrict__ Xl) {
    int wave = threadIdx.x >> 6, lane = threadIdx.x & 63;
    size_t row = (size_t)blockIdx.x * 4 + wave;
    size_t base = row * CC + lane * 4;
    float4 x = *(float4*)(X + base);
    float4 p = *(const float4*)(P + base);
    x.x += p.x; x.y += p.y; x.z += p.z; x.w += p.w;
    float sum = x.x + x.y + x.z + x.w;
    float ss = x.x * x.x + x.y * x.y + x.z * x.z + x.w * x.w;
#pragma unroll
    for (int off = 32; off; off >>= 1) {
        sum += __shfl_down(sum, off);
        ss += __shfl_down(ss, off);
    }
    sum = __shfl(sum, 0);
    ss = __shfl(ss, 0);
    float mean = sum * (1.f / 256.f);
    float var = ss * (1.f / 256.f) - mean * mean;
    float wn = rsqrtf(var + EPSV);
    float4 gg = *(const float4*)(g + lane * 4);
    float4 bb = *(const float4*)(bta + lane * 4);
    x.x = (x.x - mean) * wn * gg.x + bb.x;
    x.y = (x.y - mean) * wn * gg.y + bb.y;
    x.z = (x.z - mean) * wn * gg.z + bb.z;
    x.w = (x.w - mean) * wn * gg.w + bb.w;
    *(float4*)(X + base) = x;
    f16x4 h4, l4;
    float xv[4] = {x.x, x.y, x.z, x.w};
#pragma unroll
    for (int j = 0; j < 4; ++j) {
        hl16 s = split2(xv[j]);
        h4[j] = s.h;
        l4[j] = s.l;
    }
    *(f16x4*)&Xh[base] = h4;
    *(f16x4*)&Xl[base] = l4;
}

// ---------------------------------------------------------------------------
// Conv-path BN apply (from raw sums) + LeakyReLU + split to fp16 hi/lo.
__global__ __launch_bounds__(256) void applyc_k(const float* __restrict__ in,
                                                _Float16* __restrict__ oh,
                                                _Float16* __restrict__ ol,
                                                const float* __restrict__ st,
                                                const float* __restrict__ gam,
                                                const float* __restrict__ bet,
                                                int total, int Cc, float invM) {
    int i = blockIdx.x * 256 + threadIdx.x;
    if (i >= total) return;
    int c = i % Cc;
    float mean = st[c] * invM;
    float var = st[Cc + c] * invM - mean * mean;
    float sc = rsqrtf(var + EPSV) * gam[c];
    float v = fmaf(in[i] - mean, sc, bet[c]);
    v = v > 0.f ? v : 0.2f * v;
    hl16 s = split2(v);
    oh[i] = s.h;
    ol[i] = s.l;
}

// ---------------------------------------------------------------------------
// Fused: BN3(raw sums)+ReLU -> argmax -> ball query -> gather grouped coords.
__global__ __launch_bounds__(64) void select_k(const float* __restrict__ H3,
                                               const float* __restrict__ pts,
                                               const float* __restrict__ st,
                                               const float* __restrict__ gam,
                                               const float* __restrict__ bet,
                                               float* __restrict__ G0) {
    int bs = blockIdx.x;
    int b = bs >> 4, ch = bs & 15;
    int lane = threadIdx.x;
    float mean = st[ch] * INV_MF;
    float var = st[16 + ch] * INV_MF - mean * mean;
    float sc = rsqrtf(var + EPSV) * gam[ch];
    float sh = bet[ch] - mean * sc;
    float best = -1e30f;
    int bn = 0;
    for (int n = lane; n < NN; n += 64) {
        float v = fmaf(H3[((size_t)(b * NN + n)) * 16 + ch], sc, sh);
        v = fmaxf(v, 0.f);
        if (v > best) { best = v; bn = n; }
    }
#pragma unroll
    for (int off = 32; off; off >>= 1) {
        float ov = __shfl_xor(best, off);
        int on = __shfl_xor(bn, off);
        if (ov > best || (ov == best && on < bn)) { best = ov; bn = on; }
    }
    const float* px = pts + (size_t)b * 3 * NN;
    float qx = px[bn], qy = px[NN + bn], qz = px[2 * NN + bn];
    float qq = (qx * qx + qy * qy) + qz * qz;
    __shared__ int sgi[NSAMPLE];
    const float R2 = 0.09f;
    int cnt = 0;
    for (int base = 0; base < NN && cnt < NSAMPLE; base += 64) {
        int n = base + lane;
        float x = px[n], y = px[NN + n], z = px[2 * NN + n];
        float pp = (x * x + y * y) + z * z;
        float dot = (qx * x + qy * y) + qz * z;
        float sqd = (qq + pp) - 2.f * dot;
        bool ok = !(sqd > R2);
        unsigned long long mk = __ballot(ok);
        int pos = cnt + (int)__popcll(mk & ((1ull << lane) - 1ull));
        if (ok && pos < NSAMPLE) sgi[pos] = n;
        cnt += (int)__popcll(mk);
    }
    __syncthreads();
    int g0 = sgi[0];
    if (lane >= cnt && lane < NSAMPLE) sgi[lane] = g0;
    __syncthreads();
    for (int e = lane; e < KK * 3; e += 64) {
        int k = e / 3, d = e % 3;
        int src = (k == 0) ? bn : sgi[k - 1];
        G0[((size_t)bs * KK + k) * 3 + d] = px[d * NN + src];
    }
}

// ---------------------------------------------------------------------------
// Fused BN(C3, raw sums)+LeakyReLU+max over k.
__global__ __launch_bounds__(256) void maxpool_k(const float* __restrict__ G3,
                                                 const float* __restrict__ st,
                                                 const float* __restrict__ gam,
                                                 const float* __restrict__ bet,
                                                 float* __restrict__ out) {
    int i = blockIdx.x * 256 + threadIdx.x;
    if (i >= BB * 512 * SS) return;
    int o = i & 511;
    int s = (i >> 9) & 15;
    int b = i >> 13;
    float mean = st[o] * INV_MG;
    float var = st[512 + o] * INV_MG - mean * mean;
    float sc = rsqrtf(var + EPSV) * gam[o];
    float sh = bet[o] - mean * sc;
    const float* p = G3 + ((size_t)(b * SS + s) * KK) * 512 + o;
    float mx = -1e30f;
#pragma unroll
    for (int k = 0; k < KK; ++k) {
        float v = fmaf(p[(size_t)k * 512], sc, sh);
        v = v > 0.f ? v : 0.2f * v;
        mx = fmaxf(mx, v);
    }
    out[((size_t)(b * 512 + o)) * SS + s] = mx;
}

// ---------------------------------------------------------------------------
extern "C" void kernel_launch(void* const* d_in, const int* in_sizes, int n_in,
                              void* d_out, int out_size, void* d_ws, size_t ws_size,
                              hipStream_t stream) {
    const float* hoch = (const float*)d_in[0];
    const float* pts = (const float*)d_in[1];
    const float* Wq = (const float*)d_in[2];
    const float* Wk = (const float*)d_in[3];
    const float* Wv = (const float*)d_in[4];
    const float* Wo = (const float*)d_in[5];
    const float* ln_g = (const float*)d_in[6];
    const float* ln_b = (const float*)d_in[7];
    const float* fg_w1 = (const float*)d_in[8];
    const float* fg_b1 = (const float*)d_in[9];
    const float* fg_w2 = (const float*)d_in[10];
    const float* fg_b2 = (const float*)d_in[11];
    const float* fg_w3 = (const float*)d_in[12];
    const float* fg_b3 = (const float*)d_in[13];
    const float* fg_g1 = (const float*)d_in[14];
    const float* fg_be1 = (const float*)d_in[15];
    const float* fg_g2 = (const float*)d_in[16];
    const float* fg_be2 = (const float*)d_in[17];
    const float* fg_g3 = (const float*)d_in[18];
    const float* fg_be3 = (const float*)d_in[19];
    const float* cw1 = (const float*)d_in[20];
    const float* cw2 = (const float*)d_in[21];
    const float* cw3 = (const float*)d_in[22];
    const float* cg1 = (const float*)d_in[23];
    const float* cb1 = (const float*)d_in[24];
    const float* cg2 = (const float*)d_in[25];
    const float* cb2 = (const float*)d_in[26];
    const float* cg3 = (const float*)d_in[27];
    const float* cb3 = (const float*)d_in[28];
    float* out = (float*)d_out;

    float* ws = (float*)d_ws;
    const size_t M1 = (size_t)BB * NN * CC;  // 2,097,152
    float* X = ws;
    float* bA = ws + M1;
    float* bB = ws + 2 * M1;
    float* bC = ws + 3 * M1;
    _Float16* hb = (_Float16*)(ws + 4 * M1);
    _Float16* Xh = hb;
    _Float16* Xl = hb + M1;
    _Float16* Qh = hb + 2 * M1;  // also O (attn writes split O back here)
    _Float16* Ql = hb + 3 * M1;
    _Float16* Kh = hb + 4 * M1;  // also conv activations post-transformer
    _Float16* Kl = hb + 5 * M1;
    _Float16* Vh = hb + 6 * M1;
    _Float16* Vl = hb + 7 * M1;
    _Float16* wt = hb + 8 * M1;  // 1,376,256 halves
    float* sm = ws + 4 * M1 + (9 * M1) / 2;
    float* st1 = sm;
    float* st2 = sm + 1024;
    float* st3 = sm + 2048;
    float* st4 = sm + 3072;
    float* st5 = sm + 4096;
    float* st6 = sm + 5120;
    float* G0 = sm + 8192;  // 6336

    prep_split_k<<<2688, 256, 0, stream>>>(Wq, Wk, Wv, Wo, fg_w1, cw2, cw3, wt, sm);
    transpose_split_k<<<dim3(NN / 32, CC / 32, BB), dim3(32, 8), 0, stream>>>(hoch, X, Xh, Xl);

    const int Mrows = BB * NN;  // 8192
    for (int l = 0; l < LL; ++l) {
        qkv_h_k<<<dim3(12, Mrows / 128), 256, 0, stream>>>(Xh, Xl, wt, l, Qh, Ql, Kh, Kl, Vh, Vl);
        attn4_k<<<dim3(NN / 64, BB * HH), 256, 0, stream>>>(Qh, Ql, Kh, Kl, Vh, Vl);
        int slot = (l * 4 + 3) * 2;
        gemm_h_k<128><<<dim3(CC / 64, Mrows / 128), 256, 0, stream>>>(
            Qh, Ql, wt + (size_t)slot * WT_SLOT, wt + (size_t)(slot + 1) * WT_SLOT,
            nullptr, bA, CC, CC, nullptr);
        add_ln_k<<<Mrows / 4, 256, 0, stream>>>(X, bA, ln_g + l * CC, ln_b + l * CC, Xh, Xl);
    }

    // fg head: 256 -> 64 -> 32 -> 16; stats fused in epilogues, BN fused forward
    gemm_h_k<64><<<dim3(1, Mrows / 64), 256, 0, stream>>>(Xh, Xl, wt + FG1H_OFF, wt + FG1L_OFF, fg_b1, bA, 64, 256, st1);
    gemm_k<true, true><<<dim3(1, Mrows / 64), 256, 0, stream>>>(bA, fg_w2, fg_b2, bB, Mrows, 32, 64,
                                                                st1, fg_g1, fg_be1, INV_MF, st2);
    gemm_k<true, true><<<dim3(1, Mrows / 64), 256, 0, stream>>>(bB, fg_w3, fg_b3, bC, Mrows, 16, 32,
                                                                st2, fg_g2, fg_be2, INV_MF, st3);

    // selection + grouping (applies BN3+ReLU internally)
    select_k<<<BB * SS, 64, 0, stream>>>(bC, pts, st3, fg_g3, fg_be3, G0);

    // conv stack: 3 -> 64 -> 256 -> 512
    const int Mg = BB * SS * KK;  // 2112 = 33*64
    gemm_k<true, false><<<dim3(1, Mg / 64), 256, 0, stream>>>(G0, cw1, nullptr, bA, Mg, 64, 3,
                                                              nullptr, nullptr, nullptr, 0.f, st4);
    applyc_k<<<(Mg * 64 + 255) / 256, 256, 0, stream>>>(bA, Kh, Kl, st4, cg1, cb1, Mg * 64, 64, INV_MG);
    gemm_h_k<64><<<dim3(4, Mg / 64), 256, 0, stream>>>(Kh, Kl, wt + CW2H_OFF, wt + CW2L_OFF, nullptr, bB, 256, 64, st5);
    applyc_k<<<(Mg * 256 + 255) / 256, 256, 0, stream>>>(bB, Kh, Kl, st5, cg2, cb2, Mg * 256, 256, INV_MG);
    gemm_h_k<64><<<dim3(8, Mg / 64), 256, 0, stream>>>(Kh, Kl, wt + CW3H_OFF, wt + CW3L_OFF, nullptr, bC, 512, 256, st6);

    // fused BN(C3)+LeakyReLU+maxpool
    maxpool_k<<<(BB * 512 * SS + 255) / 256, 256, 0, stream>>>(bC, st6, cg3, cb3, out);

    (void)in_sizes; (void)n_in; (void)out_size; (void)ws_size;
}